// Round 1
// baseline (4150.109 us; speedup 1.0000x reference)
//
#include <hip/hip_runtime.h>
#include <hip/hip_bf16.h>
#include <math.h>

// Problem constants
constexpr int N_   = 4096;
constexpr int E_   = 131072;
constexpr int D_   = 256;
constexpr int DIN_ = 16;
constexpr int D3_  = 768;   // 3*D
constexpr int D2_  = 512;   // 2*D
constexpr int HD_  = 128;   // head dim

// ---- bf16 helpers (avoid __hip_bfloat16 in shared arrays) ----
__device__ __forceinline__ unsigned short f2b(float f) {
  unsigned int u = __float_as_uint(f);
  u = u + 0x7fffu + ((u >> 16) & 1u);   // round-to-nearest-even
  return (unsigned short)(u >> 16);
}
__device__ __forceinline__ float b2f(unsigned short s) {
  return __uint_as_float(((unsigned int)s) << 16);
}

// Python scalar may arrive as int32 or float32 bits; values here are small ints.
__device__ __forceinline__ float scalar_as_float(const void* p) {
  int iv = *(const int*)p;
  if (iv >= 1 && iv <= 1000000) return (float)iv;  // plausible int
  return __int_as_float(iv);                       // else float bits
}

__device__ __forceinline__ float gelu_exact(float v) {
  return 0.5f * v * (1.0f + erff(v * 0.70710678118654752f));
}

// ---------------- transpose [rows,cols] -> [cols,rows] ----------------
__global__ void k_transpose(const float* __restrict__ src, float* __restrict__ dst,
                            int rows, int cols) {
  int idx = blockIdx.x * 256 + threadIdx.x;
  if (idx < rows * cols) {
    int r = idx / cols, c = idx % cols;
    dst[(size_t)c * rows + r] = src[idx];
  }
}

// ---------------- copy (float4) ----------------
__global__ void k_copy4(const float4* __restrict__ src, float4* __restrict__ dst, int n4) {
  int idx = blockIdx.x * 256 + threadIdx.x;
  if (idx < n4) dst[idx] = src[idx];
}

// ---------------- scatter: xout[dst] += norm * (x[src] + edge_attr) ----------------
// block = 256 = 4 edges x 64 threads; each thread does one float4 of D=256
__global__ __launch_bounds__(256) void k_scatter(
    const float* __restrict__ x, const int* __restrict__ adj,
    const float* __restrict__ dmap, const float* __restrict__ nrm,
    const float* __restrict__ lin_w, const float* __restrict__ lin_b,
    float* __restrict__ xout) {
  __shared__ float s_dm[4][DIN_];
  int te = threadIdx.x >> 6;
  int d4 = threadIdx.x & 63;
  int e  = blockIdx.x * 4 + te;
  if (d4 < DIN_) s_dm[te][d4] = dmap[(size_t)e * DIN_ + d4];
  __syncthreads();
  int vs = adj[e];
  int vd = adj[E_ + e];
  float w = nrm[e];
  int d = d4 * 4;
  float4 xs = *(const float4*)(x + (size_t)vs * D_ + d);
  float ea[4];
#pragma unroll
  for (int q = 0; q < 4; q++) {
    const float* lw = lin_w + (size_t)(d + q) * DIN_;
    float acc = lin_b[d + q];
#pragma unroll
    for (int k = 0; k < DIN_; k++) acc += s_dm[te][k] * lw[k];
    ea[q] = acc;
  }
  float* op = xout + (size_t)vd * D_ + d;
  atomicAdd(op + 0, w * (xs.x + ea[0]));
  atomicAdd(op + 1, w * (xs.y + ea[1]));
  atomicAdd(op + 2, w * (xs.z + ea[2]));
  atomicAdd(op + 3, w * (xs.w + ea[3]));
}

// ---------------- C[M,N] = A[M,K] @ B[N,K]^T + bias ----------------
// 64x64 tile, BK=16, 256 threads, 4x4 micro-tile per thread
__global__ __launch_bounds__(256) void k_gemm_bt(
    const float* __restrict__ A, const float* __restrict__ B,
    const float* __restrict__ bias, float* __restrict__ C,
    int M, int Nn, int K) {
  __shared__ float sA[16][68];
  __shared__ float sB[16][68];
  int bm = blockIdx.y * 64, bn = blockIdx.x * 64;
  int tid = threadIdx.x;
  int tr = tid >> 4, tc = tid & 15;
  float acc[4][4] = {};
  for (int k0 = 0; k0 < K; k0 += 16) {
    for (int i = tid; i < 1024; i += 256) {
      int r = i >> 4, c = i & 15;
      sA[c][r] = A[(size_t)(bm + r) * K + k0 + c];
      sB[c][r] = B[(size_t)(bn + r) * K + k0 + c];
    }
    __syncthreads();
#pragma unroll
    for (int kk = 0; kk < 16; kk++) {
      float av[4], bv[4];
#pragma unroll
      for (int i = 0; i < 4; i++) av[i] = sA[kk][tr * 4 + i];
#pragma unroll
      for (int j = 0; j < 4; j++) bv[j] = sB[kk][tc * 4 + j];
#pragma unroll
      for (int i = 0; i < 4; i++)
#pragma unroll
        for (int j = 0; j < 4; j++) acc[i][j] += av[i] * bv[j];
    }
    __syncthreads();
  }
#pragma unroll
  for (int i = 0; i < 4; i++) {
    int r = bm + tr * 4 + i;
#pragma unroll
    for (int j = 0; j < 4; j++) {
      int c = bn + tc * 4 + j;
      C[(size_t)r * Nn + c] = acc[i][j] + bias[c];
    }
  }
}

// ---------------- flash attention, H=2, HD=128 ----------------
// grid (N/16, 2); QT=16 q rows/block, CK=64 keys/chunk; k & v share one LDS buffer
__global__ __launch_bounds__(256) void k_attn(const float* __restrict__ qkv,
                                              float* __restrict__ o_out) {
  const int QT = 16, CK = 64;
  __shared__ float sq[QT][132];
  __shared__ float skv[CK][132];
  __shared__ float sp[QT][68];
  __shared__ float sm[QT], sl[QT], sa[QT];
  int h  = blockIdx.y;
  int q0 = blockIdx.x * QT;
  int tid = threadIdx.x;
  for (int i = tid; i < QT * HD_; i += 256) {
    int r = i >> 7, c = i & 127;
    sq[r][c] = qkv[(size_t)(q0 + r) * D3_ + h * HD_ + c];
  }
  if (tid < QT) { sm[tid] = -1e30f; sl[tid] = 0.f; }
  int orow = tid >> 4;
  int dg   = (tid & 15) * 8;
  float oacc[8] = {};
  __syncthreads();
  for (int c0 = 0; c0 < N_; c0 += CK) {
    // load K chunk
    for (int i = tid; i < CK * HD_; i += 256) {
      int r = i >> 7, c = i & 127;
      skv[r][c] = qkv[(size_t)(c0 + r) * D3_ + D_ + h * HD_ + c];
    }
    __syncthreads();
    // scores: 16x64, 4 per thread
    {
      int r = tid >> 4, cc = (tid & 15) * 4;
      float a0 = 0, a1 = 0, a2 = 0, a3 = 0;
      for (int d = 0; d < HD_; d += 4) {
        float4 qv  = *(const float4*)&sq[r][d];
        float4 k0v = *(const float4*)&skv[cc + 0][d];
        float4 k1v = *(const float4*)&skv[cc + 1][d];
        float4 k2v = *(const float4*)&skv[cc + 2][d];
        float4 k3v = *(const float4*)&skv[cc + 3][d];
        a0 += qv.x * k0v.x + qv.y * k0v.y + qv.z * k0v.z + qv.w * k0v.w;
        a1 += qv.x * k1v.x + qv.y * k1v.y + qv.z * k1v.z + qv.w * k1v.w;
        a2 += qv.x * k2v.x + qv.y * k2v.y + qv.z * k2v.z + qv.w * k2v.w;
        a3 += qv.x * k3v.x + qv.y * k3v.y + qv.z * k3v.z + qv.w * k3v.w;
      }
      const float sc = 0.08838834764831845f; // 1/sqrt(128)
      sp[r][cc + 0] = a0 * sc;
      sp[r][cc + 1] = a1 * sc;
      sp[r][cc + 2] = a2 * sc;
      sp[r][cc + 3] = a3 * sc;
    }
    __syncthreads();
    // load V chunk (overwrites K) + online softmax (threads 0..15)
    for (int i = tid; i < CK * HD_; i += 256) {
      int r = i >> 7, c = i & 127;
      skv[r][c] = qkv[(size_t)(c0 + r) * D3_ + 2 * D_ + h * HD_ + c];
    }
    if (tid < QT) {
      float mo = sm[tid];
      float mx = mo;
      for (int j = 0; j < CK; j++) mx = fmaxf(mx, sp[tid][j]);
      float al = __expf(mo - mx);
      float s = 0.f;
      for (int j = 0; j < CK; j++) {
        float p = __expf(sp[tid][j] - mx);
        sp[tid][j] = p;
        s += p;
      }
      sl[tid] = sl[tid] * al + s;
      sm[tid] = mx;
      sa[tid] = al;
    }
    __syncthreads();
    // o update
    {
      float al = sa[orow];
#pragma unroll
      for (int q = 0; q < 8; q++) oacc[q] *= al;
      for (int j = 0; j < CK; j++) {
        float p = sp[orow][j];
        float4 v0 = *(const float4*)&skv[j][dg];
        float4 v1 = *(const float4*)&skv[j][dg + 4];
        oacc[0] += p * v0.x; oacc[1] += p * v0.y;
        oacc[2] += p * v0.z; oacc[3] += p * v0.w;
        oacc[4] += p * v1.x; oacc[5] += p * v1.y;
        oacc[6] += p * v1.z; oacc[7] += p * v1.w;
      }
    }
    __syncthreads();
  }
  float inv = 1.f / sl[orow];
  float* op = o_out + (size_t)(q0 + orow) * D_ + h * HD_ + dg;
#pragma unroll
  for (int q = 0; q < 8; q++) op[q] = oacc[q] * inv;
}

// ---------------- final combine ----------------
// out = theta*([hl|h0]@Wl + [hg|h0]@Wg) + (1-theta)*((1-a)(hl+hg) + 2a*h0)
// virtual A' [4096,1024] = [hl | h0 | hg | h0], B' [1024,256] = [Wl ; Wg]
__global__ __launch_bounds__(256) void k_final(
    const float* __restrict__ hl, const float* __restrict__ hg, const float* __restrict__ h0,
    const float* __restrict__ Wl, const float* __restrict__ Wg,
    const float* __restrict__ alpha_p, const void* lamda_p, const void* l_p,
    float* __restrict__ out) {
  __shared__ float sA[16][68];
  __shared__ float sB[16][68];
  float theta = fminf(1.f, logf(scalar_as_float(lamda_p) / scalar_as_float(l_p) + 1.f));
  float a = alpha_p[0];
  int bm = blockIdx.y * 64, bn = blockIdx.x * 64;
  int tid = threadIdx.x, tr = tid >> 4, tc = tid & 15;
  float acc[4][4] = {};
  for (int k0 = 0; k0 < 1024; k0 += 16) {
    for (int i = tid; i < 1024; i += 256) {
      int r = i >> 4, c = i & 15;
      int k = k0 + c;
      const float* src = (k < 256) ? hl : (k < 512) ? h0 : (k < 768) ? hg : h0;
      sA[c][r] = src[(size_t)(bm + r) * 256 + (k & 255)];
    }
    for (int i = tid; i < 1024; i += 256) {
      int kk = i >> 6, j = i & 63;
      int k = k0 + kk;
      const float* Bp = (k < 512) ? (Wl + (size_t)k * 256) : (Wg + (size_t)(k - 512) * 256);
      sB[kk][j] = Bp[bn + j];
    }
    __syncthreads();
#pragma unroll
    for (int kk = 0; kk < 16; kk++) {
      float av[4], bv[4];
#pragma unroll
      for (int i = 0; i < 4; i++) av[i] = sA[kk][tr * 4 + i];
#pragma unroll
      for (int j = 0; j < 4; j++) bv[j] = sB[kk][tc * 4 + j];
#pragma unroll
      for (int i = 0; i < 4; i++)
#pragma unroll
        for (int j = 0; j < 4; j++) acc[i][j] += av[i] * bv[j];
    }
    __syncthreads();
  }
  float omt = 1.f - theta;
#pragma unroll
  for (int i = 0; i < 4; i++) {
    int r = bm + tr * 4 + i;
#pragma unroll
    for (int j = 0; j < 4; j++) {
      int c = bn + tc * 4 + j;
      size_t idx = (size_t)r * 256 + c;
      out[idx] = theta * acc[i][j] + omt * ((1.f - a) * (hl[idx] + hg[idx]) + 2.f * a * h0[idx]);
    }
  }
}

// ---------------- fused edge MLP ----------------
// per block: 16 edges. h3=[xout[src]|edge_attr|xout[dst]] (bf16 LDS),
// t1=gelu(h3@w1t+b1) (bf16 LDS), t2=gelu(t1@w2t+b2) (bf16 LDS), dm_out=t2@w3^T+b3
__global__ __launch_bounds__(256) void k_edge_mlp(
    const float* __restrict__ xout, const int* __restrict__ adj,
    const float* __restrict__ dmap,
    const float* __restrict__ lin_w, const float* __restrict__ lin_b,
    const float* __restrict__ w1t, const float* __restrict__ b1,
    const float* __restrict__ w2t, const float* __restrict__ b2,
    const float* __restrict__ w3, const float* __restrict__ b3,
    float* __restrict__ dmo) {
  __shared__ unsigned short a3[16][768];   // 24 KB
  __shared__ unsigned short t1[16][512];   // 16 KB
  __shared__ unsigned short t2[16][256];   //  8 KB
  int tid = threadIdx.x;
  int e0 = blockIdx.x * 16;
  // ---- stage h3 ----
  {
    float bl = lin_b[tid];
    const float* lw = lin_w + (size_t)tid * DIN_;
    float lwr[DIN_];
#pragma unroll
    for (int k = 0; k < DIN_; k++) lwr[k] = lw[k];
    for (int e = 0; e < 16; e++) {
      int vs = adj[e0 + e], vd = adj[E_ + e0 + e];
      a3[e][tid]       = f2b(xout[(size_t)vs * D_ + tid]);
      a3[e][512 + tid] = f2b(xout[(size_t)vd * D_ + tid]);
      const float* dme = dmap + (size_t)(e0 + e) * DIN_;
      float acc = bl;
#pragma unroll
      for (int k = 0; k < DIN_; k++) acc += dme[k] * lwr[k];
      a3[e][256 + tid] = f2b(acc);
    }
  }
  __syncthreads();
  // ---- GEMM1: [16,768] @ w1t[768,512] -> t1, gelu ----
  {
    int eg = tid >> 6;              // wave -> 4 edge rows
    int j0 = (tid & 63) * 8;        // 8 output cols
    float acc[4][8];
#pragma unroll
    for (int j = 0; j < 8; j++) {
      float bb = b1[j0 + j];
#pragma unroll
      for (int i = 0; i < 4; i++) acc[i][j] = bb;
    }
    const unsigned short* ar0 = a3[eg * 4 + 0];
    const unsigned short* ar1 = a3[eg * 4 + 1];
    const unsigned short* ar2 = a3[eg * 4 + 2];
    const unsigned short* ar3 = a3[eg * 4 + 3];
    for (int k = 0; k < 768; k++) {
      float4 wa = *(const float4*)(w1t + (size_t)k * 512 + j0);
      float4 wb = *(const float4*)(w1t + (size_t)k * 512 + j0 + 4);
      float av[4];
      av[0] = b2f(ar0[k]); av[1] = b2f(ar1[k]);
      av[2] = b2f(ar2[k]); av[3] = b2f(ar3[k]);
#pragma unroll
      for (int i = 0; i < 4; i++) {
        acc[i][0] += av[i] * wa.x; acc[i][1] += av[i] * wa.y;
        acc[i][2] += av[i] * wa.z; acc[i][3] += av[i] * wa.w;
        acc[i][4] += av[i] * wb.x; acc[i][5] += av[i] * wb.y;
        acc[i][6] += av[i] * wb.z; acc[i][7] += av[i] * wb.w;
      }
    }
#pragma unroll
    for (int i = 0; i < 4; i++) {
      int e = eg * 4 + i;
#pragma unroll
      for (int j = 0; j < 8; j++) t1[e][j0 + j] = f2b(gelu_exact(acc[i][j]));
    }
  }
  __syncthreads();
  // ---- GEMM2: [16,512] @ w2t[512,256] -> t2, gelu ----
  {
    int eg = tid >> 6;
    int j0 = (tid & 63) * 4;
    float acc[4][4];
#pragma unroll
    for (int j = 0; j < 4; j++) {
      float bb = b2[j0 + j];
#pragma unroll
      for (int i = 0; i < 4; i++) acc[i][j] = bb;
    }
    const unsigned short* ar0 = t1[eg * 4 + 0];
    const unsigned short* ar1 = t1[eg * 4 + 1];
    const unsigned short* ar2 = t1[eg * 4 + 2];
    const unsigned short* ar3 = t1[eg * 4 + 3];
    for (int k = 0; k < 512; k++) {
      float4 wv = *(const float4*)(w2t + (size_t)k * 256 + j0);
      float av[4];
      av[0] = b2f(ar0[k]); av[1] = b2f(ar1[k]);
      av[2] = b2f(ar2[k]); av[3] = b2f(ar3[k]);
#pragma unroll
      for (int i = 0; i < 4; i++) {
        acc[i][0] += av[i] * wv.x; acc[i][1] += av[i] * wv.y;
        acc[i][2] += av[i] * wv.z; acc[i][3] += av[i] * wv.w;
      }
    }
#pragma unroll
    for (int i = 0; i < 4; i++) {
      int e = eg * 4 + i;
#pragma unroll
      for (int j = 0; j < 4; j++) t2[e][j0 + j] = f2b(gelu_exact(acc[i][j]));
    }
  }
  __syncthreads();
  // ---- GEMM3: [16,256] @ w3[16,256]^T -> dm_out ----
  {
    int e = tid >> 4, j = tid & 15;
    const float* w3r = w3 + (size_t)j * 256;
    float acc = b3[j];
    for (int k = 0; k < 256; k++) acc += b2f(t2[e][k]) * w3r[k];
    dmo[(size_t)(e0 + e) * DIN_ + j] = acc;
  }
}

extern "C" void kernel_launch(void* const* d_in, const int* in_sizes, int n_in,
                              void* d_out, int out_size, void* d_ws, size_t ws_size,
                              hipStream_t stream) {
  const float* input = (const float*)d_in[0];
  const int*   adj   = (const int*)d_in[1];
  const float* h0    = (const float*)d_in[2];
  const void*  lamda = d_in[3];
  const float* alpha = (const float*)d_in[4];
  const void*  lll   = d_in[5];
  const float* dmap  = (const float*)d_in[6];
  const float* nrm   = (const float*)d_in[7];
  const float* Wl    = (const float*)d_in[8];
  const float* Wg    = (const float*)d_in[9];
  const float* lin_w = (const float*)d_in[10];
  const float* lin_b = (const float*)d_in[11];
  const float* w1    = (const float*)d_in[12];
  const float* b1    = (const float*)d_in[13];
  const float* w2    = (const float*)d_in[14];
  const float* b2    = (const float*)d_in[15];
  const float* w3    = (const float*)d_in[16];
  const float* b3    = (const float*)d_in[17];
  const float* ipw   = (const float*)d_in[18];
  const float* ipb   = (const float*)d_in[19];
  const float* opw   = (const float*)d_in[20];
  const float* opb   = (const float*)d_in[21];
  float* out = (float*)d_out;

  float* ws   = (float*)d_ws;
  float* xout = ws;                               // N*D        = 1,048,576
  float* qkv  = xout + (size_t)N_ * D_;           // N*3D       = 3,145,728
  float* atto = qkv  + (size_t)N_ * 3 * D_;       // N*D
  float* hgl  = atto + (size_t)N_ * D_;           // N*D
  float* w1t  = hgl  + (size_t)N_ * D_;           // 768*512
  float* w2t  = w1t  + (size_t)D3_ * D2_;         // 512*256
  // total ~28 MB of ws

  // weight transposes ([out,in] -> [in,out] for coalesced streaming)
  k_transpose<<<dim3((512 * 768 + 255) / 256), 256, 0, stream>>>(w1, w1t, 512, 768);
  k_transpose<<<dim3((256 * 512 + 255) / 256), 256, 0, stream>>>(w2, w2t, 256, 512);

  // x_out = input, then scatter-add messages
  k_copy4<<<dim3(N_ * D_ / 4 / 256), 256, 0, stream>>>((const float4*)input, (float4*)xout,
                                                       N_ * D_ / 4);
  k_scatter<<<dim3(E_ / 4), 256, 0, stream>>>(input, adj, dmap, nrm, lin_w, lin_b, xout);

  // MHA: qkv -> flash attention -> out_proj
  k_gemm_bt<<<dim3(D3_ / 64, N_ / 64), 256, 0, stream>>>(input, ipw, ipb, qkv, N_, D3_, D_);
  k_attn<<<dim3(N_ / 16, 2), 256, 0, stream>>>(qkv, atto);
  k_gemm_bt<<<dim3(D_ / 64, N_ / 64), 256, 0, stream>>>(atto, opw, opb, hgl, N_, D_, D_);

  // output[N,D]
  k_final<<<dim3(4, N_ / 64), 256, 0, stream>>>(xout, hgl, h0, Wl, Wg, alpha, lamda, lll, out);

  // dm_out[E,16]
  k_edge_mlp<<<dim3(E_ / 16), 256, 0, stream>>>(xout, adj, dmap, lin_w, lin_b,
                                                w1t, b1, w2t, b2, w3, b3,
                                                out + (size_t)N_ * D_);
}

// Round 2
// 2603.223 us; speedup vs baseline: 1.5942x; 1.5942x over previous
//
#include <hip/hip_runtime.h>
#include <hip/hip_bf16.h>
#include <math.h>

// Problem constants
constexpr int N_   = 4096;
constexpr int E_   = 131072;
constexpr int D_   = 256;
constexpr int DIN_ = 16;
constexpr int D3_  = 768;   // 3*D
constexpr int HD_  = 128;   // head dim

typedef __bf16 bf16_8 __attribute__((ext_vector_type(8)));
typedef float  f32x4  __attribute__((ext_vector_type(4)));

// ---- bf16 helpers ----
__device__ __forceinline__ unsigned short f2b(float f) {
  unsigned int u = __float_as_uint(f);
  u = u + 0x7fffu + ((u >> 16) & 1u);   // round-to-nearest-even
  return (unsigned short)(u >> 16);
}
__device__ __forceinline__ float b2f(unsigned short s) {
  return __uint_as_float(((unsigned int)s) << 16);
}
__device__ __forceinline__ unsigned int pack2(unsigned short lo, unsigned short hi) {
  return (unsigned int)lo | ((unsigned int)hi << 16);
}
__device__ __forceinline__ bf16_8 frag16(const unsigned short* p) {
  uint4 v = *(const uint4*)p;           // 16B load (LDS b128 or global dwordx4)
  return __builtin_bit_cast(bf16_8, v);
}

// Python scalar may arrive as int32 or float32 bits; values here are small ints.
__device__ __forceinline__ float scalar_as_float(const void* p) {
  int iv = *(const int*)p;
  if (iv >= 1 && iv <= 1000000) return (float)iv;  // plausible int
  return __int_as_float(iv);                       // else float bits
}

__device__ __forceinline__ float gelu_exact(float v) {
  return 0.5f * v * (1.0f + erff(v * 0.70710678118654752f));
}

// ---------------- f32 -> bf16 convert ----------------
__global__ void k_f2b(const float* __restrict__ src, unsigned short* __restrict__ dst, int n) {
  int i = blockIdx.x * 256 + threadIdx.x;
  if (i < n) dst[i] = f2b(src[i]);
}

// ---------------- copy (float4) ----------------
__global__ void k_copy4(const float4* __restrict__ src, float4* __restrict__ dst, int n4) {
  int idx = blockIdx.x * 256 + threadIdx.x;
  if (idx < n4) dst[idx] = src[idx];
}

// ---------------- scatter: xout[dst] += norm * (x[src] + edge_attr) ----------------
__global__ __launch_bounds__(256) void k_scatter(
    const float* __restrict__ x, const int* __restrict__ adj,
    const float* __restrict__ dmap, const float* __restrict__ nrm,
    const float* __restrict__ lin_w, const float* __restrict__ lin_b,
    float* __restrict__ xout) {
  __shared__ float s_dm[4][DIN_];
  int te = threadIdx.x >> 6;
  int d4 = threadIdx.x & 63;
  int e  = blockIdx.x * 4 + te;
  if (d4 < DIN_) s_dm[te][d4] = dmap[(size_t)e * DIN_ + d4];
  __syncthreads();
  int vs = adj[e];
  int vd = adj[E_ + e];
  float w = nrm[e];
  int d = d4 * 4;
  float4 xs = *(const float4*)(x + (size_t)vs * D_ + d);
  float ea[4];
#pragma unroll
  for (int q = 0; q < 4; q++) {
    const float* lw = lin_w + (size_t)(d + q) * DIN_;
    float acc = lin_b[d + q];
#pragma unroll
    for (int k = 0; k < DIN_; k++) acc += s_dm[te][k] * lw[k];
    ea[q] = acc;
  }
  float* op = xout + (size_t)vd * D_ + d;
  atomicAdd(op + 0, w * (xs.x + ea[0]));
  atomicAdd(op + 1, w * (xs.y + ea[1]));
  atomicAdd(op + 2, w * (xs.z + ea[2]));
  atomicAdd(op + 3, w * (xs.w + ea[3]));
}

// ---------------- C[M,N] = A[M,K] @ B[N,K]^T + bias ----------------
__global__ __launch_bounds__(256) void k_gemm_bt(
    const float* __restrict__ A, const float* __restrict__ B,
    const float* __restrict__ bias, float* __restrict__ C,
    int M, int Nn, int K) {
  __shared__ float sA[16][68];
  __shared__ float sB[16][68];
  int bm = blockIdx.y * 64, bn = blockIdx.x * 64;
  int tid = threadIdx.x;
  int tr = tid >> 4, tc = tid & 15;
  float acc[4][4] = {};
  for (int k0 = 0; k0 < K; k0 += 16) {
    for (int i = tid; i < 1024; i += 256) {
      int r = i >> 4, c = i & 15;
      sA[c][r] = A[(size_t)(bm + r) * K + k0 + c];
      sB[c][r] = B[(size_t)(bn + r) * K + k0 + c];
    }
    __syncthreads();
#pragma unroll
    for (int kk = 0; kk < 16; kk++) {
      float av[4], bv[4];
#pragma unroll
      for (int i = 0; i < 4; i++) av[i] = sA[kk][tr * 4 + i];
#pragma unroll
      for (int j = 0; j < 4; j++) bv[j] = sB[kk][tc * 4 + j];
#pragma unroll
      for (int i = 0; i < 4; i++)
#pragma unroll
        for (int j = 0; j < 4; j++) acc[i][j] += av[i] * bv[j];
    }
    __syncthreads();
  }
#pragma unroll
  for (int i = 0; i < 4; i++) {
    int r = bm + tr * 4 + i;
#pragma unroll
    for (int j = 0; j < 4; j++) {
      int c = bn + tc * 4 + j;
      C[(size_t)r * Nn + c] = acc[i][j] + bias[c];
    }
  }
}

// ---------------- flash attention, H=2, HD=128 ----------------
__global__ __launch_bounds__(256) void k_attn(const float* __restrict__ qkv,
                                              float* __restrict__ o_out) {
  const int QT = 16, CK = 64;
  __shared__ float sq[QT][132];
  __shared__ float skv[CK][132];
  __shared__ float sp[QT][68];
  __shared__ float sm[QT], sl[QT], sa[QT];
  int h  = blockIdx.y;
  int q0 = blockIdx.x * QT;
  int tid = threadIdx.x;
  for (int i = tid; i < QT * HD_; i += 256) {
    int r = i >> 7, c = i & 127;
    sq[r][c] = qkv[(size_t)(q0 + r) * D3_ + h * HD_ + c];
  }
  if (tid < QT) { sm[tid] = -1e30f; sl[tid] = 0.f; }
  int orow = tid >> 4;
  int dg   = (tid & 15) * 8;
  float oacc[8] = {};
  __syncthreads();
  for (int c0 = 0; c0 < N_; c0 += CK) {
    for (int i = tid; i < CK * HD_; i += 256) {
      int r = i >> 7, c = i & 127;
      skv[r][c] = qkv[(size_t)(c0 + r) * D3_ + D_ + h * HD_ + c];
    }
    __syncthreads();
    {
      int r = tid >> 4, cc = (tid & 15) * 4;
      float a0 = 0, a1 = 0, a2 = 0, a3 = 0;
      for (int d = 0; d < HD_; d += 4) {
        float4 qv  = *(const float4*)&sq[r][d];
        float4 k0v = *(const float4*)&skv[cc + 0][d];
        float4 k1v = *(const float4*)&skv[cc + 1][d];
        float4 k2v = *(const float4*)&skv[cc + 2][d];
        float4 k3v = *(const float4*)&skv[cc + 3][d];
        a0 += qv.x * k0v.x + qv.y * k0v.y + qv.z * k0v.z + qv.w * k0v.w;
        a1 += qv.x * k1v.x + qv.y * k1v.y + qv.z * k1v.z + qv.w * k1v.w;
        a2 += qv.x * k2v.x + qv.y * k2v.y + qv.z * k2v.z + qv.w * k2v.w;
        a3 += qv.x * k3v.x + qv.y * k3v.y + qv.z * k3v.z + qv.w * k3v.w;
      }
      const float sc = 0.08838834764831845f; // 1/sqrt(128)
      sp[r][cc + 0] = a0 * sc;
      sp[r][cc + 1] = a1 * sc;
      sp[r][cc + 2] = a2 * sc;
      sp[r][cc + 3] = a3 * sc;
    }
    __syncthreads();
    for (int i = tid; i < CK * HD_; i += 256) {
      int r = i >> 7, c = i & 127;
      skv[r][c] = qkv[(size_t)(c0 + r) * D3_ + 2 * D_ + h * HD_ + c];
    }
    if (tid < QT) {
      float mo = sm[tid];
      float mx = mo;
      for (int j = 0; j < CK; j++) mx = fmaxf(mx, sp[tid][j]);
      float al = __expf(mo - mx);
      float s = 0.f;
      for (int j = 0; j < CK; j++) {
        float p = __expf(sp[tid][j] - mx);
        sp[tid][j] = p;
        s += p;
      }
      sl[tid] = sl[tid] * al + s;
      sm[tid] = mx;
      sa[tid] = al;
    }
    __syncthreads();
    {
      float al = sa[orow];
#pragma unroll
      for (int q = 0; q < 8; q++) oacc[q] *= al;
      for (int j = 0; j < CK; j++) {
        float p = sp[orow][j];
        float4 v0 = *(const float4*)&skv[j][dg];
        float4 v1 = *(const float4*)&skv[j][dg + 4];
        oacc[0] += p * v0.x; oacc[1] += p * v0.y;
        oacc[2] += p * v0.z; oacc[3] += p * v0.w;
        oacc[4] += p * v1.x; oacc[5] += p * v1.y;
        oacc[6] += p * v1.z; oacc[7] += p * v1.w;
      }
    }
    __syncthreads();
  }
  float inv = 1.f / sl[orow];
  float* op = o_out + (size_t)(q0 + orow) * D_ + h * HD_ + dg;
#pragma unroll
  for (int q = 0; q < 8; q++) op[q] = oacc[q] * inv;
}

// ---------------- final combine ----------------
__global__ __launch_bounds__(256) void k_final(
    const float* __restrict__ hl, const float* __restrict__ hg, const float* __restrict__ h0,
    const float* __restrict__ Wl, const float* __restrict__ Wg,
    const float* __restrict__ alpha_p, const void* lamda_p, const void* l_p,
    float* __restrict__ out) {
  __shared__ float sA[16][68];
  __shared__ float sB[16][68];
  float theta = fminf(1.f, logf(scalar_as_float(lamda_p) / scalar_as_float(l_p) + 1.f));
  float a = alpha_p[0];
  int bm = blockIdx.y * 64, bn = blockIdx.x * 64;
  int tid = threadIdx.x, tr = tid >> 4, tc = tid & 15;
  float acc[4][4] = {};
  for (int k0 = 0; k0 < 1024; k0 += 16) {
    for (int i = tid; i < 1024; i += 256) {
      int r = i >> 4, c = i & 15;
      int k = k0 + c;
      const float* src = (k < 256) ? hl : (k < 512) ? h0 : (k < 768) ? hg : h0;
      sA[c][r] = src[(size_t)(bm + r) * 256 + (k & 255)];
    }
    for (int i = tid; i < 1024; i += 256) {
      int kk = i >> 6, j = i & 63;
      int k = k0 + kk;
      const float* Bp = (k < 512) ? (Wl + (size_t)k * 256) : (Wg + (size_t)(k - 512) * 256);
      sB[kk][j] = Bp[bn + j];
    }
    __syncthreads();
#pragma unroll
    for (int kk = 0; kk < 16; kk++) {
      float av[4], bv[4];
#pragma unroll
      for (int i = 0; i < 4; i++) av[i] = sA[kk][tr * 4 + i];
#pragma unroll
      for (int j = 0; j < 4; j++) bv[j] = sB[kk][tc * 4 + j];
#pragma unroll
      for (int i = 0; i < 4; i++)
#pragma unroll
        for (int j = 0; j < 4; j++) acc[i][j] += av[i] * bv[j];
    }
    __syncthreads();
  }
  float omt = 1.f - theta;
#pragma unroll
  for (int i = 0; i < 4; i++) {
    int r = bm + tr * 4 + i;
#pragma unroll
    for (int j = 0; j < 4; j++) {
      int c = bn + tc * 4 + j;
      size_t idx = (size_t)r * 256 + c;
      out[idx] = theta * acc[i][j] + omt * ((1.f - a) * (hl[idx] + hg[idx]) + 2.f * a * h0[idx]);
    }
  }
}

// ---------------- fused edge MLP, MFMA version ----------------
// 32 edges/block. A-chunks [32x128] staged in LDS bf16; weights pre-converted
// bf16, native [out,in] layout == B-fragment layout (lane reads 8 contig k at
// row n). t1 [32x520], t2 [32x264] bf16 in LDS (pad +8 keeps 16B alignment,
// bank stride 4). LDS total 50176 B -> 3 blocks/CU.
__global__ __launch_bounds__(256, 3) void k_edge_mlp_mfma(
    const float* __restrict__ xout, const int* __restrict__ adj,
    const float* __restrict__ dmap,
    const float* __restrict__ lin_w, const float* __restrict__ lin_b,
    const unsigned short* __restrict__ wb1, const float* __restrict__ b1,
    const unsigned short* __restrict__ wb2, const float* __restrict__ b2,
    const unsigned short* __restrict__ wb3, const float* __restrict__ b3,
    float* __restrict__ dmo) {
  __shared__ unsigned short sLo[8448];        // sA [32][136] aliased with sT2 [32][264]
  __shared__ unsigned short sT1[32][520];     // 33280 B
  unsigned short (*sA)[136]  = (unsigned short(*)[136])sLo;
  unsigned short (*sT2)[264] = (unsigned short(*)[264])sLo;

  const int tid  = threadIdx.x;
  const int e0   = blockIdx.x * 32;
  const int lane = tid & 63;
  const int wv   = tid >> 6;
  const int r16  = lane & 15;
  const int quad = lane >> 4;

  const f32x4 zz = {0.f, 0.f, 0.f, 0.f};
  f32x4 acc1[8][2];
#pragma unroll
  for (int i = 0; i < 8; ++i) { acc1[i][0] = zz; acc1[i][1] = zz; }

  // ---- GEMM1: h3[32,768] @ wb1^T -> t1[32,512], k-chunks of 128 ----
  for (int c = 0; c < 6; ++c) {
    const int k0 = c * 128;
    __syncthreads();  // prev chunk's sA reads done
    {
      int r = tid >> 3, t8 = tid & 7;
      int e = e0 + r;
      unsigned short* dstp = &sA[r][t8 * 16];
      unsigned short tmp[16];
      if (c == 2 || c == 3) {
        // edge_attr cols
        float dm[DIN_];
        const float* dmp = dmap + (size_t)e * DIN_;
#pragma unroll
        for (int q = 0; q < DIN_; ++q) dm[q] = dmp[q];
        int jb = (c - 2) * 128 + t8 * 16;
#pragma unroll
        for (int j = 0; j < 16; ++j) {
          const float* lw = lin_w + (size_t)(jb + j) * DIN_;
          float acc = lin_b[jb + j];
#pragma unroll
          for (int q = 0; q < DIN_; ++q) acc += dm[q] * lw[q];
          tmp[j] = f2b(acc);
        }
      } else {
        int node = (c < 2) ? adj[e] : adj[E_ + e];
        const float* src = xout + (size_t)node * D_ + (c & 1) * 128 + t8 * 16;
#pragma unroll
        for (int q = 0; q < 16; q += 4) {
          float4 v = *(const float4*)(src + q);
          tmp[q] = f2b(v.x); tmp[q + 1] = f2b(v.y);
          tmp[q + 2] = f2b(v.z); tmp[q + 3] = f2b(v.w);
        }
      }
      uint4 w0 = {pack2(tmp[0], tmp[1]),  pack2(tmp[2], tmp[3]),
                  pack2(tmp[4], tmp[5]),  pack2(tmp[6], tmp[7])};
      uint4 w1v = {pack2(tmp[8], tmp[9]),  pack2(tmp[10], tmp[11]),
                   pack2(tmp[12], tmp[13]), pack2(tmp[14], tmp[15])};
      *(uint4*)(dstp) = w0;
      *(uint4*)(dstp + 8) = w1v;
    }
    __syncthreads();
#pragma unroll
    for (int kk = 0; kk < 4; ++kk) {
      bf16_8 a0 = frag16(&sA[r16][kk * 32 + quad * 8]);
      bf16_8 a1 = frag16(&sA[16 + r16][kk * 32 + quad * 8]);
#pragma unroll
      for (int i = 0; i < 8; ++i) {
        const unsigned short* bp =
            wb1 + (size_t)(wv * 128 + i * 16 + r16) * 768 + k0 + kk * 32 + quad * 8;
        bf16_8 bf = frag16(bp);
        acc1[i][0] = __builtin_amdgcn_mfma_f32_16x16x32_bf16(a0, bf, acc1[i][0], 0, 0, 0);
        acc1[i][1] = __builtin_amdgcn_mfma_f32_16x16x32_bf16(a1, bf, acc1[i][1], 0, 0, 0);
      }
    }
  }
  // epilogue 1: bias + gelu -> sT1 (bf16)
#pragma unroll
  for (int i = 0; i < 8; ++i) {
    int col = wv * 128 + i * 16 + r16;
    float bb = b1[col];
#pragma unroll
    for (int m = 0; m < 2; ++m)
#pragma unroll
      for (int r = 0; r < 4; ++r) {
        int row = m * 16 + quad * 4 + r;
        sT1[row][col] = f2b(gelu_exact(acc1[i][m][r] + bb));
      }
  }
  __syncthreads();

  // ---- GEMM2: t1[32,512] @ wb2^T -> t2[32,256] ----
  f32x4 acc2[4][2];
#pragma unroll
  for (int i = 0; i < 4; ++i) { acc2[i][0] = zz; acc2[i][1] = zz; }
#pragma unroll 4
  for (int ks = 0; ks < 16; ++ks) {
    bf16_8 a0 = frag16(&sT1[r16][ks * 32 + quad * 8]);
    bf16_8 a1 = frag16(&sT1[16 + r16][ks * 32 + quad * 8]);
#pragma unroll
    for (int i = 0; i < 4; ++i) {
      const unsigned short* bp =
          wb2 + (size_t)(wv * 64 + i * 16 + r16) * 512 + ks * 32 + quad * 8;
      bf16_8 bf = frag16(bp);
      acc2[i][0] = __builtin_amdgcn_mfma_f32_16x16x32_bf16(a0, bf, acc2[i][0], 0, 0, 0);
      acc2[i][1] = __builtin_amdgcn_mfma_f32_16x16x32_bf16(a1, bf, acc2[i][1], 0, 0, 0);
    }
  }
  // epilogue 2: bias + gelu -> sT2 (aliases sA; all sA reads completed pre-barrier)
#pragma unroll
  for (int i = 0; i < 4; ++i) {
    int col = wv * 64 + i * 16 + r16;
    float bb = b2[col];
#pragma unroll
    for (int m = 0; m < 2; ++m)
#pragma unroll
      for (int r = 0; r < 4; ++r) {
        int row = m * 16 + quad * 4 + r;
        sT2[row][col] = f2b(gelu_exact(acc2[i][m][r] + bb));
      }
  }
  __syncthreads();

  // ---- GEMM3: t2[32,256] @ wb3^T -> dm_out[32,16] ----
  if (wv < 2) {
    f32x4 acc3 = zz;
#pragma unroll
    for (int ks = 0; ks < 8; ++ks) {
      bf16_8 a = frag16(&sT2[wv * 16 + r16][ks * 32 + quad * 8]);
      bf16_8 b = frag16(wb3 + (size_t)r16 * 256 + ks * 32 + quad * 8);
      acc3 = __builtin_amdgcn_mfma_f32_16x16x32_bf16(a, b, acc3, 0, 0, 0);
    }
    float bb = b3[r16];
#pragma unroll
    for (int r = 0; r < 4; ++r) {
      int row = wv * 16 + quad * 4 + r;
      dmo[(size_t)(e0 + row) * DIN_ + r16] = acc3[r] + bb;
    }
  }
}

extern "C" void kernel_launch(void* const* d_in, const int* in_sizes, int n_in,
                              void* d_out, int out_size, void* d_ws, size_t ws_size,
                              hipStream_t stream) {
  const float* input = (const float*)d_in[0];
  const int*   adj   = (const int*)d_in[1];
  const float* h0    = (const float*)d_in[2];
  const void*  lamda = d_in[3];
  const float* alpha = (const float*)d_in[4];
  const void*  lll   = d_in[5];
  const float* dmap  = (const float*)d_in[6];
  const float* nrm   = (const float*)d_in[7];
  const float* Wl    = (const float*)d_in[8];
  const float* Wg    = (const float*)d_in[9];
  const float* lin_w = (const float*)d_in[10];
  const float* lin_b = (const float*)d_in[11];
  const float* w1    = (const float*)d_in[12];
  const float* b1    = (const float*)d_in[13];
  const float* w2    = (const float*)d_in[14];
  const float* b2    = (const float*)d_in[15];
  const float* w3    = (const float*)d_in[16];
  const float* b3    = (const float*)d_in[17];
  const float* ipw   = (const float*)d_in[18];
  const float* ipb   = (const float*)d_in[19];
  const float* opw   = (const float*)d_in[20];
  const float* opb   = (const float*)d_in[21];
  float* out = (float*)d_out;

  float* ws   = (float*)d_ws;
  float* xout = ws;                               // N*D
  float* qkv  = xout + (size_t)N_ * D_;           // N*3D
  float* atto = qkv  + (size_t)N_ * 3 * D_;       // N*D
  float* hgl  = atto + (size_t)N_ * D_;           // N*D
  unsigned short* wb1 = (unsigned short*)(hgl + (size_t)N_ * D_);  // 512*768
  unsigned short* wb2 = wb1 + 512 * 768;          // 256*512
  unsigned short* wb3 = wb2 + 256 * 512;          // 16*256
  // total ~26.2 MB of ws

  // bf16 weight conversion (native [out,in] layout == MFMA B-frag layout)
  k_f2b<<<dim3((512 * 768 + 255) / 256), 256, 0, stream>>>(w1, wb1, 512 * 768);
  k_f2b<<<dim3((256 * 512 + 255) / 256), 256, 0, stream>>>(w2, wb2, 256 * 512);
  k_f2b<<<dim3((16 * 256 + 255) / 256), 256, 0, stream>>>(w3, wb3, 16 * 256);

  // x_out = input, then scatter-add messages
  k_copy4<<<dim3(N_ * D_ / 4 / 256), 256, 0, stream>>>((const float4*)input, (float4*)xout,
                                                       N_ * D_ / 4);
  k_scatter<<<dim3(E_ / 4), 256, 0, stream>>>(input, adj, dmap, nrm, lin_w, lin_b, xout);

  // MHA: qkv -> flash attention -> out_proj
  k_gemm_bt<<<dim3(D3_ / 64, N_ / 64), 256, 0, stream>>>(input, ipw, ipb, qkv, N_, D3_, D_);
  k_attn<<<dim3(N_ / 16, 2), 256, 0, stream>>>(qkv, atto);
  k_gemm_bt<<<dim3(D_ / 64, N_ / 64), 256, 0, stream>>>(atto, opw, opb, hgl, N_, D_, D_);

  // output[N,D]
  k_final<<<dim3(4, N_ / 64), 256, 0, stream>>>(xout, hgl, h0, Wl, Wg, alpha, lamda, lll, out);

  // dm_out[E,16]
  k_edge_mlp_mfma<<<dim3(E_ / 32), 256, 0, stream>>>(xout, adj, dmap, lin_w, lin_b,
                                                     wb1, b1, wb2, b2, wb3, b3,
                                                     out + (size_t)N_ * D_);
}

// Round 3
// 1731.118 us; speedup vs baseline: 2.3974x; 1.5038x over previous
//
#include <hip/hip_runtime.h>
#include <hip/hip_bf16.h>
#include <math.h>

// Problem constants
constexpr int N_   = 4096;
constexpr int E_   = 131072;
constexpr int D_   = 256;
constexpr int DIN_ = 16;
constexpr int D3_  = 768;   // 3*D
constexpr int HD_  = 128;   // head dim

typedef __bf16 bf16_8 __attribute__((ext_vector_type(8)));
typedef float  f32x4  __attribute__((ext_vector_type(4)));

// ---- bf16 helpers ----
__device__ __forceinline__ unsigned short f2b(float f) {
  unsigned int u = __float_as_uint(f);
  u = u + 0x7fffu + ((u >> 16) & 1u);   // round-to-nearest-even
  return (unsigned short)(u >> 16);
}
__device__ __forceinline__ float b2f(unsigned short s) {
  return __uint_as_float(((unsigned int)s) << 16);
}
__device__ __forceinline__ unsigned int pack2(unsigned short lo, unsigned short hi) {
  return (unsigned int)lo | ((unsigned int)hi << 16);
}
__device__ __forceinline__ bf16_8 frag16(const unsigned short* p) {
  uint4 v = *(const uint4*)p;           // 16B load (LDS b128 or global dwordx4)
  return __builtin_bit_cast(bf16_8, v);
}

// Python scalar may arrive as int32 or float32 bits; values here are small ints.
__device__ __forceinline__ float scalar_as_float(const void* p) {
  int iv = *(const int*)p;
  if (iv >= 1 && iv <= 1000000) return (float)iv;  // plausible int
  return __int_as_float(iv);                       // else float bits
}

__device__ __forceinline__ float gelu_exact(float v) {
  return 0.5f * v * (1.0f + erff(v * 0.70710678118654752f));
}

// ---------------- f32 -> bf16 convert ----------------
__global__ void k_f2b(const float* __restrict__ src, unsigned short* __restrict__ dst, int n) {
  int i = blockIdx.x * 256 + threadIdx.x;
  if (i < n) dst[i] = f2b(src[i]);
}

// ---------------- copy (float4) ----------------
__global__ void k_copy4(const float4* __restrict__ src, float4* __restrict__ dst, int n4) {
  int idx = blockIdx.x * 256 + threadIdx.x;
  if (idx < n4) dst[idx] = src[idx];
}

// ---------------- scatter: xout[dst] += norm * (x[src] + edge_attr) ----------------
__global__ __launch_bounds__(256) void k_scatter(
    const float* __restrict__ x, const int* __restrict__ adj,
    const float* __restrict__ dmap, const float* __restrict__ nrm,
    const float* __restrict__ lin_w, const float* __restrict__ lin_b,
    float* __restrict__ xout) {
  __shared__ float s_dm[4][DIN_];
  int te = threadIdx.x >> 6;
  int d4 = threadIdx.x & 63;
  int e  = blockIdx.x * 4 + te;
  if (d4 < DIN_) s_dm[te][d4] = dmap[(size_t)e * DIN_ + d4];
  __syncthreads();
  int vs = adj[e];
  int vd = adj[E_ + e];
  float w = nrm[e];
  int d = d4 * 4;
  float4 xs = *(const float4*)(x + (size_t)vs * D_ + d);
  float ea[4];
#pragma unroll
  for (int q = 0; q < 4; q++) {
    const float* lw = lin_w + (size_t)(d + q) * DIN_;
    float acc = lin_b[d + q];
#pragma unroll
    for (int k = 0; k < DIN_; k++) acc += s_dm[te][k] * lw[k];
    ea[q] = acc;
  }
  float* op = xout + (size_t)vd * D_ + d;
  atomicAdd(op + 0, w * (xs.x + ea[0]));
  atomicAdd(op + 1, w * (xs.y + ea[1]));
  atomicAdd(op + 2, w * (xs.z + ea[2]));
  atomicAdd(op + 3, w * (xs.w + ea[3]));
}

// ---------------- C[M,N] = A[M,K] @ B[N,K]^T + bias ----------------
__global__ __launch_bounds__(256) void k_gemm_bt(
    const float* __restrict__ A, const float* __restrict__ B,
    const float* __restrict__ bias, float* __restrict__ C,
    int M, int Nn, int K) {
  __shared__ float sA[16][68];
  __shared__ float sB[16][68];
  int bm = blockIdx.y * 64, bn = blockIdx.x * 64;
  int tid = threadIdx.x;
  int tr = tid >> 4, tc = tid & 15;
  float acc[4][4] = {};
  for (int k0 = 0; k0 < K; k0 += 16) {
    for (int i = tid; i < 1024; i += 256) {
      int r = i >> 4, c = i & 15;
      sA[c][r] = A[(size_t)(bm + r) * K + k0 + c];
      sB[c][r] = B[(size_t)(bn + r) * K + k0 + c];
    }
    __syncthreads();
#pragma unroll
    for (int kk = 0; kk < 16; kk++) {
      float av[4], bv[4];
#pragma unroll
      for (int i = 0; i < 4; i++) av[i] = sA[kk][tr * 4 + i];
#pragma unroll
      for (int j = 0; j < 4; j++) bv[j] = sB[kk][tc * 4 + j];
#pragma unroll
      for (int i = 0; i < 4; i++)
#pragma unroll
        for (int j = 0; j < 4; j++) acc[i][j] += av[i] * bv[j];
    }
    __syncthreads();
  }
#pragma unroll
  for (int i = 0; i < 4; i++) {
    int r = bm + tr * 4 + i;
#pragma unroll
    for (int j = 0; j < 4; j++) {
      int c = bn + tc * 4 + j;
      C[(size_t)r * Nn + c] = acc[i][j] + bias[c];
    }
  }
}

// ---------------- qkv split: fp32 [N,768] -> bf16 Qb/Kb [h][n][128] ----------------
__global__ void k_qk2b(const float* __restrict__ qkv,
                       unsigned short* __restrict__ Qb, unsigned short* __restrict__ Kb) {
  int off = (blockIdx.x * 256 + threadIdx.x) * 8;   // over N*512
  int n = off >> 9, c = off & 511;
  const float* src = qkv + (size_t)n * D3_ + c;     // Q cols 0..255, K cols 256..511
  float4 a = *(const float4*)src;
  float4 b = *(const float4*)(src + 4);
  uint4 p = {pack2(f2b(a.x), f2b(a.y)), pack2(f2b(a.z), f2b(a.w)),
             pack2(f2b(b.x), f2b(b.y)), pack2(f2b(b.z), f2b(b.w))};
  int cc = c & 255;
  int hh = cc >> 7, d = cc & 127;
  unsigned short* dst = (c < 256 ? Qb : Kb) + (size_t)hh * N_ * HD_ + (size_t)n * HD_ + d;
  *(uint4*)dst = p;
}

// ---------------- V transpose: fp32 qkv V-cols -> bf16 Vt [h][128][N] ----------------
__global__ __launch_bounds__(256) void k_v2t(const float* __restrict__ qkv,
                                             unsigned short* __restrict__ Vt) {
  __shared__ unsigned short sv[64][136];
  int h = blockIdx.y;
  int n0 = blockIdx.x * 64;
  int tid = threadIdx.x;
#pragma unroll
  for (int it = 0; it < 4; ++it) {
    int off = (tid + it * 256) * 8;
    int r = off >> 7, d = off & 127;
    const float* src = qkv + (size_t)(n0 + r) * D3_ + 2 * D_ + h * HD_ + d;
    float4 a = *(const float4*)src;
    float4 b = *(const float4*)(src + 4);
    uint4 p = {pack2(f2b(a.x), f2b(a.y)), pack2(f2b(a.z), f2b(a.w)),
               pack2(f2b(b.x), f2b(b.y)), pack2(f2b(b.z), f2b(b.w))};
    *(uint4*)&sv[r][d] = p;
  }
  __syncthreads();
#pragma unroll
  for (int it = 0; it < 4; ++it) {
    int off = (tid + it * 256) * 8;
    int d = off >> 6, k = off & 63;
    unsigned short t[8];
#pragma unroll
    for (int j = 0; j < 8; ++j) t[j] = sv[k + j][d];
    uint4 p = {pack2(t[0], t[1]), pack2(t[2], t[3]),
               pack2(t[4], t[5]), pack2(t[6], t[7])};
    *(uint4*)(Vt + (size_t)h * HD_ * N_ + (size_t)d * N_ + n0 + k) = p;
  }
}

// ---------------- MFMA flash attention, H=2, HD=128 ----------------
// Q tile 16 rows/block, grid (N/16, 2) = 512 blocks. 64-key chunks.
// S=QK^T via 16x16x32 MFMA (1 n-tile/wave), online softmax (16 lanes/row),
// PV via MFMA with pre-transposed V (B-frag reads 8 contiguous keys).
__global__ __launch_bounds__(256) void k_attn_mfma(
    const unsigned short* __restrict__ Qb, const unsigned short* __restrict__ Kb,
    const unsigned short* __restrict__ Vt, float* __restrict__ o_out) {
  __shared__ unsigned short sK[64][136];   // keys x dims (+8 pad)
  __shared__ unsigned short sV[128][72];   // dims x keys (+8 pad)
  __shared__ float          sS[16][68];    // scores
  __shared__ unsigned short sP[16][72];    // probs bf16 (A-frag layout)
  __shared__ float sm[16], sl[16], sa[16];

  const int tid  = threadIdx.x;
  const int h    = blockIdx.y;
  const int q0   = blockIdx.x * 16;
  const int lane = tid & 63;
  const int wv   = tid >> 6;
  const int r16  = lane & 15;
  const int quad = lane >> 4;

  // Q fragments (A operand) — same for all 4 waves
  bf16_8 qf[4];
#pragma unroll
  for (int kk = 0; kk < 4; ++kk)
    qf[kk] = frag16(Qb + (size_t)h * N_ * HD_ + (size_t)(q0 + r16) * HD_ + kk * 32 + quad * 8);

  if (tid < 16) { sm[tid] = -1e30f; sl[tid] = 0.f; }

  const f32x4 zz = {0.f, 0.f, 0.f, 0.f};
  f32x4 o0 = zz, o1 = zz;   // output dims wv*32+[0,16), wv*32+[16,32)

  const unsigned short* Kh = Kb + (size_t)h * N_ * HD_;
  const unsigned short* Vh = Vt + (size_t)h * HD_ * N_;

  for (int c0 = 0; c0 < N_; c0 += 64) {
    __syncthreads();   // prior PV reads / init visible
    // stage K chunk [64][128]
#pragma unroll
    for (int it = 0; it < 4; ++it) {
      int off = (tid + it * 256) * 8;
      int key = off >> 7, d = off & 127;
      *(uint4*)&sK[key][d] = *(const uint4*)(Kh + (size_t)(c0 + key) * HD_ + d);
    }
    // stage V^T chunk [128][64]
#pragma unroll
    for (int it = 0; it < 4; ++it) {
      int off = (tid + it * 256) * 8;
      int d = off >> 6, k = off & 63;
      *(uint4*)&sV[d][k] = *(const uint4*)(Vh + (size_t)d * N_ + c0 + k);
    }
    __syncthreads();
    // S = Q K^T for keys [wv*16, wv*16+16)
    f32x4 s = zz;
#pragma unroll
    for (int kk = 0; kk < 4; ++kk) {
      bf16_8 bf = frag16(&sK[wv * 16 + r16][kk * 32 + quad * 8]);
      s = __builtin_amdgcn_mfma_f32_16x16x32_bf16(qf[kk], bf, s, 0, 0, 0);
    }
    const float sc = 0.08838834764831845f;   // 1/sqrt(128)
#pragma unroll
    for (int r = 0; r < 4; ++r)
      sS[quad * 4 + r][wv * 16 + r16] = s[r] * sc;
    __syncthreads();
    // online softmax: 16 threads per q-row
    {
      int row = tid >> 4, i = tid & 15;
      float4 v = *(const float4*)&sS[row][i * 4];
      float mx = fmaxf(fmaxf(v.x, v.y), fmaxf(v.z, v.w));
#pragma unroll
      for (int m = 1; m <= 8; m <<= 1) mx = fmaxf(mx, __shfl_xor(mx, m));
      float mo = sm[row];
      float mn = fmaxf(mo, mx);
      float p0 = __expf(v.x - mn), p1 = __expf(v.y - mn);
      float p2 = __expf(v.z - mn), p3 = __expf(v.w - mn);
      float ps = p0 + p1 + p2 + p3;
#pragma unroll
      for (int m = 1; m <= 8; m <<= 1) ps += __shfl_xor(ps, m);
      uint2 pk = {pack2(f2b(p0), f2b(p1)), pack2(f2b(p2), f2b(p3))};
      *(uint2*)&sP[row][i * 4] = pk;
      if (i == 0) {
        float al = __expf(mo - mn);
        sl[row] = sl[row] * al + ps;
        sm[row] = mn;
        sa[row] = al;
      }
    }
    __syncthreads();
    // O rescale + PV accumulate
    {
      float al0 = sa[quad * 4 + 0], al1 = sa[quad * 4 + 1];
      float al2 = sa[quad * 4 + 2], al3 = sa[quad * 4 + 3];
      o0[0] *= al0; o0[1] *= al1; o0[2] *= al2; o0[3] *= al3;
      o1[0] *= al0; o1[1] *= al1; o1[2] *= al2; o1[3] *= al3;
#pragma unroll
      for (int kk = 0; kk < 2; ++kk) {
        bf16_8 pa = frag16(&sP[r16][kk * 32 + quad * 8]);
        bf16_8 v0 = frag16(&sV[wv * 32 + r16][kk * 32 + quad * 8]);
        bf16_8 v1 = frag16(&sV[wv * 32 + 16 + r16][kk * 32 + quad * 8]);
        o0 = __builtin_amdgcn_mfma_f32_16x16x32_bf16(pa, v0, o0, 0, 0, 0);
        o1 = __builtin_amdgcn_mfma_f32_16x16x32_bf16(pa, v1, o1, 0, 0, 0);
      }
    }
  }
  // epilogue: divide by l, store fp32
  {
    float i0 = 1.f / sl[quad * 4 + 0], i1 = 1.f / sl[quad * 4 + 1];
    float i2 = 1.f / sl[quad * 4 + 2], i3 = 1.f / sl[quad * 4 + 3];
    float* base = o_out + (size_t)q0 * D_ + h * HD_ + wv * 32 + r16;
    base[(size_t)(quad * 4 + 0) * D_] = o0[0] * i0;
    base[(size_t)(quad * 4 + 1) * D_] = o0[1] * i1;
    base[(size_t)(quad * 4 + 2) * D_] = o0[2] * i2;
    base[(size_t)(quad * 4 + 3) * D_] = o0[3] * i3;
    float* base1 = base + 16;
    base1[(size_t)(quad * 4 + 0) * D_] = o1[0] * i0;
    base1[(size_t)(quad * 4 + 1) * D_] = o1[1] * i1;
    base1[(size_t)(quad * 4 + 2) * D_] = o1[2] * i2;
    base1[(size_t)(quad * 4 + 3) * D_] = o1[3] * i3;
  }
}

// ---------------- final combine ----------------
__global__ __launch_bounds__(256) void k_final(
    const float* __restrict__ hl, const float* __restrict__ hg, const float* __restrict__ h0,
    const float* __restrict__ Wl, const float* __restrict__ Wg,
    const float* __restrict__ alpha_p, const void* lamda_p, const void* l_p,
    float* __restrict__ out) {
  __shared__ float sA[16][68];
  __shared__ float sB[16][68];
  float theta = fminf(1.f, logf(scalar_as_float(lamda_p) / scalar_as_float(l_p) + 1.f));
  float a = alpha_p[0];
  int bm = blockIdx.y * 64, bn = blockIdx.x * 64;
  int tid = threadIdx.x, tr = tid >> 4, tc = tid & 15;
  float acc[4][4] = {};
  for (int k0 = 0; k0 < 1024; k0 += 16) {
    for (int i = tid; i < 1024; i += 256) {
      int r = i >> 4, c = i & 15;
      int k = k0 + c;
      const float* src = (k < 256) ? hl : (k < 512) ? h0 : (k < 768) ? hg : h0;
      sA[c][r] = src[(size_t)(bm + r) * 256 + (k & 255)];
    }
    for (int i = tid; i < 1024; i += 256) {
      int kk = i >> 6, j = i & 63;
      int k = k0 + kk;
      const float* Bp = (k < 512) ? (Wl + (size_t)k * 256) : (Wg + (size_t)(k - 512) * 256);
      sB[kk][j] = Bp[bn + j];
    }
    __syncthreads();
#pragma unroll
    for (int kk = 0; kk < 16; kk++) {
      float av[4], bv[4];
#pragma unroll
      for (int i = 0; i < 4; i++) av[i] = sA[kk][tr * 4 + i];
#pragma unroll
      for (int j = 0; j < 4; j++) bv[j] = sB[kk][tc * 4 + j];
#pragma unroll
      for (int i = 0; i < 4; i++)
#pragma unroll
        for (int j = 0; j < 4; j++) acc[i][j] += av[i] * bv[j];
    }
    __syncthreads();
  }
  float omt = 1.f - theta;
#pragma unroll
  for (int i = 0; i < 4; i++) {
    int r = bm + tr * 4 + i;
#pragma unroll
    for (int j = 0; j < 4; j++) {
      int c = bn + tc * 4 + j;
      size_t idx = (size_t)r * 256 + c;
      out[idx] = theta * acc[i][j] + omt * ((1.f - a) * (hl[idx] + hg[idx]) + 2.f * a * h0[idx]);
    }
  }
}

// ---------------- fused edge MLP, MFMA version ----------------
__global__ __launch_bounds__(256, 3) void k_edge_mlp_mfma(
    const float* __restrict__ xout, const int* __restrict__ adj,
    const float* __restrict__ dmap,
    const float* __restrict__ lin_w, const float* __restrict__ lin_b,
    const unsigned short* __restrict__ wb1, const float* __restrict__ b1,
    const unsigned short* __restrict__ wb2, const float* __restrict__ b2,
    const unsigned short* __restrict__ wb3, const float* __restrict__ b3,
    float* __restrict__ dmo) {
  __shared__ unsigned short sLo[8448];        // sA [32][136] aliased with sT2 [32][264]
  __shared__ unsigned short sT1[32][520];     // 33280 B
  unsigned short (*sA)[136]  = (unsigned short(*)[136])sLo;
  unsigned short (*sT2)[264] = (unsigned short(*)[264])sLo;

  const int tid  = threadIdx.x;
  const int e0   = blockIdx.x * 32;
  const int lane = tid & 63;
  const int wv   = tid >> 6;
  const int r16  = lane & 15;
  const int quad = lane >> 4;

  const f32x4 zz = {0.f, 0.f, 0.f, 0.f};
  f32x4 acc1[8][2];
#pragma unroll
  for (int i = 0; i < 8; ++i) { acc1[i][0] = zz; acc1[i][1] = zz; }

  // ---- GEMM1: h3[32,768] @ wb1^T -> t1[32,512], k-chunks of 128 ----
  for (int c = 0; c < 6; ++c) {
    const int k0 = c * 128;
    __syncthreads();
    {
      int r = tid >> 3, t8 = tid & 7;
      int e = e0 + r;
      unsigned short* dstp = &sA[r][t8 * 16];
      unsigned short tmp[16];
      if (c == 2 || c == 3) {
        float dm[DIN_];
        const float* dmp = dmap + (size_t)e * DIN_;
#pragma unroll
        for (int q = 0; q < DIN_; ++q) dm[q] = dmp[q];
        int jb = (c - 2) * 128 + t8 * 16;
#pragma unroll
        for (int j = 0; j < 16; ++j) {
          const float* lw = lin_w + (size_t)(jb + j) * DIN_;
          float acc = lin_b[jb + j];
#pragma unroll
          for (int q = 0; q < DIN_; ++q) acc += dm[q] * lw[q];
          tmp[j] = f2b(acc);
        }
      } else {
        int node = (c < 2) ? adj[e] : adj[E_ + e];
        const float* src = xout + (size_t)node * D_ + (c & 1) * 128 + t8 * 16;
#pragma unroll
        for (int q = 0; q < 16; q += 4) {
          float4 v = *(const float4*)(src + q);
          tmp[q] = f2b(v.x); tmp[q + 1] = f2b(v.y);
          tmp[q + 2] = f2b(v.z); tmp[q + 3] = f2b(v.w);
        }
      }
      uint4 w0 = {pack2(tmp[0], tmp[1]),  pack2(tmp[2], tmp[3]),
                  pack2(tmp[4], tmp[5]),  pack2(tmp[6], tmp[7])};
      uint4 w1v = {pack2(tmp[8], tmp[9]),  pack2(tmp[10], tmp[11]),
                   pack2(tmp[12], tmp[13]), pack2(tmp[14], tmp[15])};
      *(uint4*)(dstp) = w0;
      *(uint4*)(dstp + 8) = w1v;
    }
    __syncthreads();
#pragma unroll
    for (int kk = 0; kk < 4; ++kk) {
      bf16_8 a0 = frag16(&sA[r16][kk * 32 + quad * 8]);
      bf16_8 a1 = frag16(&sA[16 + r16][kk * 32 + quad * 8]);
#pragma unroll
      for (int i = 0; i < 8; ++i) {
        const unsigned short* bp =
            wb1 + (size_t)(wv * 128 + i * 16 + r16) * 768 + k0 + kk * 32 + quad * 8;
        bf16_8 bf = frag16(bp);
        acc1[i][0] = __builtin_amdgcn_mfma_f32_16x16x32_bf16(a0, bf, acc1[i][0], 0, 0, 0);
        acc1[i][1] = __builtin_amdgcn_mfma_f32_16x16x32_bf16(a1, bf, acc1[i][1], 0, 0, 0);
      }
    }
  }
#pragma unroll
  for (int i = 0; i < 8; ++i) {
    int col = wv * 128 + i * 16 + r16;
    float bb = b1[col];
#pragma unroll
    for (int m = 0; m < 2; ++m)
#pragma unroll
      for (int r = 0; r < 4; ++r) {
        int row = m * 16 + quad * 4 + r;
        sT1[row][col] = f2b(gelu_exact(acc1[i][m][r] + bb));
      }
  }
  __syncthreads();

  // ---- GEMM2: t1[32,512] @ wb2^T -> t2[32,256] ----
  f32x4 acc2[4][2];
#pragma unroll
  for (int i = 0; i < 4; ++i) { acc2[i][0] = zz; acc2[i][1] = zz; }
#pragma unroll 4
  for (int ks = 0; ks < 16; ++ks) {
    bf16_8 a0 = frag16(&sT1[r16][ks * 32 + quad * 8]);
    bf16_8 a1 = frag16(&sT1[16 + r16][ks * 32 + quad * 8]);
#pragma unroll
    for (int i = 0; i < 4; ++i) {
      const unsigned short* bp =
          wb2 + (size_t)(wv * 64 + i * 16 + r16) * 512 + ks * 32 + quad * 8;
      bf16_8 bf = frag16(bp);
      acc2[i][0] = __builtin_amdgcn_mfma_f32_16x16x32_bf16(a0, bf, acc2[i][0], 0, 0, 0);
      acc2[i][1] = __builtin_amdgcn_mfma_f32_16x16x32_bf16(a1, bf, acc2[i][1], 0, 0, 0);
    }
  }
#pragma unroll
  for (int i = 0; i < 4; ++i) {
    int col = wv * 64 + i * 16 + r16;
    float bb = b2[col];
#pragma unroll
    for (int m = 0; m < 2; ++m)
#pragma unroll
      for (int r = 0; r < 4; ++r) {
        int row = m * 16 + quad * 4 + r;
        sT2[row][col] = f2b(gelu_exact(acc2[i][m][r] + bb));
      }
  }
  __syncthreads();

  // ---- GEMM3: t2[32,256] @ wb3^T -> dm_out[32,16] ----
  if (wv < 2) {
    f32x4 acc3 = zz;
#pragma unroll
    for (int ks = 0; ks < 8; ++ks) {
      bf16_8 a = frag16(&sT2[wv * 16 + r16][ks * 32 + quad * 8]);
      bf16_8 b = frag16(wb3 + (size_t)r16 * 256 + ks * 32 + quad * 8);
      acc3 = __builtin_amdgcn_mfma_f32_16x16x32_bf16(a, b, acc3, 0, 0, 0);
    }
    float bb = b3[r16];
#pragma unroll
    for (int r = 0; r < 4; ++r) {
      int row = wv * 16 + quad * 4 + r;
      dmo[(size_t)(e0 + row) * DIN_ + r16] = acc3[r] + bb;
    }
  }
}

extern "C" void kernel_launch(void* const* d_in, const int* in_sizes, int n_in,
                              void* d_out, int out_size, void* d_ws, size_t ws_size,
                              hipStream_t stream) {
  const float* input = (const float*)d_in[0];
  const int*   adj   = (const int*)d_in[1];
  const float* h0    = (const float*)d_in[2];
  const void*  lamda = d_in[3];
  const float* alpha = (const float*)d_in[4];
  const void*  lll   = d_in[5];
  const float* dmap  = (const float*)d_in[6];
  const float* nrm   = (const float*)d_in[7];
  const float* Wl    = (const float*)d_in[8];
  const float* Wg    = (const float*)d_in[9];
  const float* lin_w = (const float*)d_in[10];
  const float* lin_b = (const float*)d_in[11];
  const float* w1    = (const float*)d_in[12];
  const float* b1    = (const float*)d_in[13];
  const float* w2    = (const float*)d_in[14];
  const float* b2    = (const float*)d_in[15];
  const float* w3    = (const float*)d_in[16];
  const float* b3    = (const float*)d_in[17];
  const float* ipw   = (const float*)d_in[18];
  const float* ipb   = (const float*)d_in[19];
  const float* opw   = (const float*)d_in[20];
  const float* opb   = (const float*)d_in[21];
  float* out = (float*)d_out;

  float* ws   = (float*)d_ws;
  float* xout = ws;                               // N*D f32
  float* qkv  = xout + (size_t)N_ * D_;           // N*3D f32
  float* atto = qkv  + (size_t)N_ * 3 * D_;       // N*D f32
  float* hgl  = atto + (size_t)N_ * D_;           // N*D f32
  unsigned short* wb1 = (unsigned short*)(hgl + (size_t)N_ * D_);  // 512*768
  unsigned short* wb2 = wb1 + 512 * 768;          // 256*512
  unsigned short* wb3 = wb2 + 256 * 512;          // 16*256
  unsigned short* Qb  = wb3 + 16 * 256;           // 2*N*128
  unsigned short* Kb  = Qb + 2 * N_ * HD_;        // 2*N*128
  unsigned short* Vt  = Kb + 2 * N_ * HD_;        // 2*128*N
  // total ~32.5 MB of ws

  // bf16 weight conversion (native [out,in] layout == MFMA B-frag layout)
  k_f2b<<<dim3((512 * 768 + 255) / 256), 256, 0, stream>>>(w1, wb1, 512 * 768);
  k_f2b<<<dim3((256 * 512 + 255) / 256), 256, 0, stream>>>(w2, wb2, 256 * 512);
  k_f2b<<<dim3((16 * 256 + 255) / 256), 256, 0, stream>>>(w3, wb3, 16 * 256);

  // x_out = input, then scatter-add messages
  k_copy4<<<dim3(N_ * D_ / 4 / 256), 256, 0, stream>>>((const float4*)input, (float4*)xout,
                                                       N_ * D_ / 4);
  k_scatter<<<dim3(E_ / 4), 256, 0, stream>>>(input, adj, dmap, nrm, lin_w, lin_b, xout);

  // MHA: qkv proj -> bf16 split/transpose -> MFMA flash attention -> out_proj
  k_gemm_bt<<<dim3(D3_ / 64, N_ / 64), 256, 0, stream>>>(input, ipw, ipb, qkv, N_, D3_, D_);
  k_qk2b<<<dim3(N_ * 512 / 8 / 256), 256, 0, stream>>>(qkv, Qb, Kb);
  k_v2t<<<dim3(N_ / 64, 2), 256, 0, stream>>>(qkv, Vt);
  k_attn_mfma<<<dim3(N_ / 16, 2), 256, 0, stream>>>(Qb, Kb, Vt, atto);
  k_gemm_bt<<<dim3(D_ / 64, N_ / 64), 256, 0, stream>>>(atto, opw, opb, hgl, N_, D_, D_);

  // output[N,D]
  k_final<<<dim3(4, N_ / 64), 256, 0, stream>>>(xout, hgl, h0, Wl, Wg, alpha, lamda, lll, out);

  // dm_out[E,16]
  k_edge_mlp_mfma<<<dim3(E_ / 32), 256, 0, stream>>>(xout, adj, dmap, lin_w, lin_b,
                                                     wb1, b1, wb2, b2, wb3, b3,
                                                     out + (size_t)N_ * D_);
}

// Round 4
// 1714.121 us; speedup vs baseline: 2.4211x; 1.0099x over previous
//
#include <hip/hip_runtime.h>
#include <hip/hip_bf16.h>
#include <math.h>

// Problem constants
constexpr int N_   = 4096;
constexpr int E_   = 131072;
constexpr int D_   = 256;
constexpr int DIN_ = 16;
constexpr int D3_  = 768;   // 3*D
constexpr int HD_  = 128;   // head dim

typedef __bf16 bf16_8 __attribute__((ext_vector_type(8)));
typedef float  f32x4  __attribute__((ext_vector_type(4)));
typedef float  f32x4v __attribute__((ext_vector_type(4)));

// ---- bf16 helpers ----
__device__ __forceinline__ unsigned short f2b(float f) {
  unsigned int u = __float_as_uint(f);
  u = u + 0x7fffu + ((u >> 16) & 1u);   // round-to-nearest-even
  return (unsigned short)(u >> 16);
}
__device__ __forceinline__ float b2f(unsigned short s) {
  return __uint_as_float(((unsigned int)s) << 16);
}
__device__ __forceinline__ unsigned int pack2(unsigned short lo, unsigned short hi) {
  return (unsigned int)lo | ((unsigned int)hi << 16);
}
__device__ __forceinline__ bf16_8 frag16(const unsigned short* p) {
  uint4 v = *(const uint4*)p;           // 16B load (LDS b128 or global dwordx4)
  return __builtin_bit_cast(bf16_8, v);
}
__device__ __forceinline__ float4 ntload4(const void* p) {
  f32x4v v = __builtin_nontemporal_load((const f32x4v*)p);
  float4 r;
  r.x = v[0]; r.y = v[1]; r.z = v[2]; r.w = v[3];
  return r;
}

// Python scalar may arrive as int32 or float32 bits; values here are small ints.
__device__ __forceinline__ float scalar_as_float(const void* p) {
  int iv = *(const int*)p;
  if (iv >= 1 && iv <= 1000000) return (float)iv;  // plausible int
  return __int_as_float(iv);                       // else float bits
}

__device__ __forceinline__ float gelu_exact(float v) {
  return 0.5f * v * (1.0f + erff(v * 0.70710678118654752f));
}

// ---------------- f32 -> bf16 convert ----------------
__global__ void k_f2b(const float* __restrict__ src, unsigned short* __restrict__ dst, int n) {
  int i = blockIdx.x * 256 + threadIdx.x;
  if (i < n) dst[i] = f2b(src[i]);
}

// ---------------- copy (float4) ----------------
__global__ void k_copy4(const float4* __restrict__ src, float4* __restrict__ dst, int n4) {
  int idx = blockIdx.x * 256 + threadIdx.x;
  if (idx < n4) dst[idx] = src[idx];
}

// ---------------- scatter: xout[dst] += norm * (x[src] + edge_attr) ----------------
__global__ __launch_bounds__(256) void k_scatter(
    const float* __restrict__ x, const int* __restrict__ adj,
    const float* __restrict__ dmap, const float* __restrict__ nrm,
    const float* __restrict__ lin_w, const float* __restrict__ lin_b,
    float* __restrict__ xout) {
  __shared__ float s_dm[4][DIN_];
  int te = threadIdx.x >> 6;
  int d4 = threadIdx.x & 63;
  int e  = blockIdx.x * 4 + te;
  if (d4 < DIN_) s_dm[te][d4] = dmap[(size_t)e * DIN_ + d4];
  __syncthreads();
  int vs = adj[e];
  int vd = adj[E_ + e];
  float w = nrm[e];
  int d = d4 * 4;
  float4 xs = *(const float4*)(x + (size_t)vs * D_ + d);
  float ea[4];
#pragma unroll
  for (int q = 0; q < 4; q++) {
    const float* lw = lin_w + (size_t)(d + q) * DIN_;
    float acc = lin_b[d + q];
#pragma unroll
    for (int k = 0; k < DIN_; k++) acc += s_dm[te][k] * lw[k];
    ea[q] = acc;
  }
  float* op = xout + (size_t)vd * D_ + d;
  atomicAdd(op + 0, w * (xs.x + ea[0]));
  atomicAdd(op + 1, w * (xs.y + ea[1]));
  atomicAdd(op + 2, w * (xs.z + ea[2]));
  atomicAdd(op + 3, w * (xs.w + ea[3]));
}

// ---------------- C[M,N] = A[M,K] @ B[N,K]^T + bias ----------------
__global__ __launch_bounds__(256) void k_gemm_bt(
    const float* __restrict__ A, const float* __restrict__ B,
    const float* __restrict__ bias, float* __restrict__ C,
    int M, int Nn, int K) {
  __shared__ float sA[16][68];
  __shared__ float sB[16][68];
  int bm = blockIdx.y * 64, bn = blockIdx.x * 64;
  int tid = threadIdx.x;
  int tr = tid >> 4, tc = tid & 15;
  float acc[4][4] = {};
  for (int k0 = 0; k0 < K; k0 += 16) {
    for (int i = tid; i < 1024; i += 256) {
      int r = i >> 4, c = i & 15;
      sA[c][r] = A[(size_t)(bm + r) * K + k0 + c];
      sB[c][r] = B[(size_t)(bn + r) * K + k0 + c];
    }
    __syncthreads();
#pragma unroll
    for (int kk = 0; kk < 16; kk++) {
      float av[4], bv[4];
#pragma unroll
      for (int i = 0; i < 4; i++) av[i] = sA[kk][tr * 4 + i];
#pragma unroll
      for (int j = 0; j < 4; j++) bv[j] = sB[kk][tc * 4 + j];
#pragma unroll
      for (int i = 0; i < 4; i++)
#pragma unroll
        for (int j = 0; j < 4; j++) acc[i][j] += av[i] * bv[j];
    }
    __syncthreads();
  }
#pragma unroll
  for (int i = 0; i < 4; i++) {
    int r = bm + tr * 4 + i;
#pragma unroll
    for (int j = 0; j < 4; j++) {
      int c = bn + tc * 4 + j;
      C[(size_t)r * Nn + c] = acc[i][j] + bias[c];
    }
  }
}

// ---------------- qkv split: fp32 [N,768] -> bf16 Qb/Kb [h][n][128] ----------------
__global__ void k_qk2b(const float* __restrict__ qkv,
                       unsigned short* __restrict__ Qb, unsigned short* __restrict__ Kb) {
  int off = (blockIdx.x * 256 + threadIdx.x) * 8;   // over N*512
  int n = off >> 9, c = off & 511;
  const float* src = qkv + (size_t)n * D3_ + c;     // Q cols 0..255, K cols 256..511
  float4 a = *(const float4*)src;
  float4 b = *(const float4*)(src + 4);
  uint4 p = {pack2(f2b(a.x), f2b(a.y)), pack2(f2b(a.z), f2b(a.w)),
             pack2(f2b(b.x), f2b(b.y)), pack2(f2b(b.z), f2b(b.w))};
  int cc = c & 255;
  int hh = cc >> 7, d = cc & 127;
  unsigned short* dst = (c < 256 ? Qb : Kb) + (size_t)hh * N_ * HD_ + (size_t)n * HD_ + d;
  *(uint4*)dst = p;
}

// ---------------- V transpose: fp32 qkv V-cols -> bf16 Vt [h][128][N] ----------------
__global__ __launch_bounds__(256) void k_v2t(const float* __restrict__ qkv,
                                             unsigned short* __restrict__ Vt) {
  __shared__ unsigned short sv[64][136];
  int h = blockIdx.y;
  int n0 = blockIdx.x * 64;
  int tid = threadIdx.x;
#pragma unroll
  for (int it = 0; it < 4; ++it) {
    int off = (tid + it * 256) * 8;
    int r = off >> 7, d = off & 127;
    const float* src = qkv + (size_t)(n0 + r) * D3_ + 2 * D_ + h * HD_ + d;
    float4 a = *(const float4*)src;
    float4 b = *(const float4*)(src + 4);
    uint4 p = {pack2(f2b(a.x), f2b(a.y)), pack2(f2b(a.z), f2b(a.w)),
               pack2(f2b(b.x), f2b(b.y)), pack2(f2b(b.z), f2b(b.w))};
    *(uint4*)&sv[r][d] = p;
  }
  __syncthreads();
#pragma unroll
  for (int it = 0; it < 4; ++it) {
    int off = (tid + it * 256) * 8;
    int d = off >> 6, k = off & 63;
    unsigned short t[8];
#pragma unroll
    for (int j = 0; j < 8; ++j) t[j] = sv[k + j][d];
    uint4 p = {pack2(t[0], t[1]), pack2(t[2], t[3]),
               pack2(t[4], t[5]), pack2(t[6], t[7])};
    *(uint4*)(Vt + (size_t)h * HD_ * N_ + (size_t)d * N_ + n0 + k) = p;
  }
}

// ---------------- MFMA flash attention, H=2, HD=128 ----------------
__global__ __launch_bounds__(256) void k_attn_mfma(
    const unsigned short* __restrict__ Qb, const unsigned short* __restrict__ Kb,
    const unsigned short* __restrict__ Vt, float* __restrict__ o_out) {
  __shared__ unsigned short sK[64][136];   // keys x dims (+8 pad)
  __shared__ unsigned short sV[128][72];   // dims x keys (+8 pad)
  __shared__ float          sS[16][68];    // scores
  __shared__ unsigned short sP[16][72];    // probs bf16 (A-frag layout)
  __shared__ float sm[16], sl[16], sa[16];

  const int tid  = threadIdx.x;
  const int h    = blockIdx.y;
  const int q0   = blockIdx.x * 16;
  const int lane = tid & 63;
  const int wv   = tid >> 6;
  const int r16  = lane & 15;
  const int quad = lane >> 4;

  bf16_8 qf[4];
#pragma unroll
  for (int kk = 0; kk < 4; ++kk)
    qf[kk] = frag16(Qb + (size_t)h * N_ * HD_ + (size_t)(q0 + r16) * HD_ + kk * 32 + quad * 8);

  if (tid < 16) { sm[tid] = -1e30f; sl[tid] = 0.f; }

  const f32x4 zz = {0.f, 0.f, 0.f, 0.f};
  f32x4 o0 = zz, o1 = zz;

  const unsigned short* Kh = Kb + (size_t)h * N_ * HD_;
  const unsigned short* Vh = Vt + (size_t)h * HD_ * N_;

  for (int c0 = 0; c0 < N_; c0 += 64) {
    __syncthreads();
#pragma unroll
    for (int it = 0; it < 4; ++it) {
      int off = (tid + it * 256) * 8;
      int key = off >> 7, d = off & 127;
      *(uint4*)&sK[key][d] = *(const uint4*)(Kh + (size_t)(c0 + key) * HD_ + d);
    }
#pragma unroll
    for (int it = 0; it < 4; ++it) {
      int off = (tid + it * 256) * 8;
      int d = off >> 6, k = off & 63;
      *(uint4*)&sV[d][k] = *(const uint4*)(Vh + (size_t)d * N_ + c0 + k);
    }
    __syncthreads();
    f32x4 s = zz;
#pragma unroll
    for (int kk = 0; kk < 4; ++kk) {
      bf16_8 bf = frag16(&sK[wv * 16 + r16][kk * 32 + quad * 8]);
      s = __builtin_amdgcn_mfma_f32_16x16x32_bf16(qf[kk], bf, s, 0, 0, 0);
    }
    const float sc = 0.08838834764831845f;   // 1/sqrt(128)
#pragma unroll
    for (int r = 0; r < 4; ++r)
      sS[quad * 4 + r][wv * 16 + r16] = s[r] * sc;
    __syncthreads();
    {
      int row = tid >> 4, i = tid & 15;
      float4 v = *(const float4*)&sS[row][i * 4];
      float mx = fmaxf(fmaxf(v.x, v.y), fmaxf(v.z, v.w));
#pragma unroll
      for (int m = 1; m <= 8; m <<= 1) mx = fmaxf(mx, __shfl_xor(mx, m));
      float mo = sm[row];
      float mn = fmaxf(mo, mx);
      float p0 = __expf(v.x - mn), p1 = __expf(v.y - mn);
      float p2 = __expf(v.z - mn), p3 = __expf(v.w - mn);
      float ps = p0 + p1 + p2 + p3;
#pragma unroll
      for (int m = 1; m <= 8; m <<= 1) ps += __shfl_xor(ps, m);
      uint2 pk = {pack2(f2b(p0), f2b(p1)), pack2(f2b(p2), f2b(p3))};
      *(uint2*)&sP[row][i * 4] = pk;
      if (i == 0) {
        float al = __expf(mo - mn);
        sl[row] = sl[row] * al + ps;
        sm[row] = mn;
        sa[row] = al;
      }
    }
    __syncthreads();
    {
      float al0 = sa[quad * 4 + 0], al1 = sa[quad * 4 + 1];
      float al2 = sa[quad * 4 + 2], al3 = sa[quad * 4 + 3];
      o0[0] *= al0; o0[1] *= al1; o0[2] *= al2; o0[3] *= al3;
      o1[0] *= al0; o1[1] *= al1; o1[2] *= al2; o1[3] *= al3;
#pragma unroll
      for (int kk = 0; kk < 2; ++kk) {
        bf16_8 pa = frag16(&sP[r16][kk * 32 + quad * 8]);
        bf16_8 v0 = frag16(&sV[wv * 32 + r16][kk * 32 + quad * 8]);
        bf16_8 v1 = frag16(&sV[wv * 32 + 16 + r16][kk * 32 + quad * 8]);
        o0 = __builtin_amdgcn_mfma_f32_16x16x32_bf16(pa, v0, o0, 0, 0, 0);
        o1 = __builtin_amdgcn_mfma_f32_16x16x32_bf16(pa, v1, o1, 0, 0, 0);
      }
    }
  }
  {
    float i0 = 1.f / sl[quad * 4 + 0], i1 = 1.f / sl[quad * 4 + 1];
    float i2 = 1.f / sl[quad * 4 + 2], i3 = 1.f / sl[quad * 4 + 3];
    float* base = o_out + (size_t)q0 * D_ + h * HD_ + wv * 32 + r16;
    base[(size_t)(quad * 4 + 0) * D_] = o0[0] * i0;
    base[(size_t)(quad * 4 + 1) * D_] = o0[1] * i1;
    base[(size_t)(quad * 4 + 2) * D_] = o0[2] * i2;
    base[(size_t)(quad * 4 + 3) * D_] = o0[3] * i3;
    float* base1 = base + 16;
    base1[(size_t)(quad * 4 + 0) * D_] = o1[0] * i0;
    base1[(size_t)(quad * 4 + 1) * D_] = o1[1] * i1;
    base1[(size_t)(quad * 4 + 2) * D_] = o1[2] * i2;
    base1[(size_t)(quad * 4 + 3) * D_] = o1[3] * i3;
  }
}

// ---------------- final combine ----------------
__global__ __launch_bounds__(256) void k_final(
    const float* __restrict__ hl, const float* __restrict__ hg, const float* __restrict__ h0,
    const float* __restrict__ Wl, const float* __restrict__ Wg,
    const float* __restrict__ alpha_p, const void* lamda_p, const void* l_p,
    float* __restrict__ out) {
  __shared__ float sA[16][68];
  __shared__ float sB[16][68];
  float theta = fminf(1.f, logf(scalar_as_float(lamda_p) / scalar_as_float(l_p) + 1.f));
  float a = alpha_p[0];
  int bm = blockIdx.y * 64, bn = blockIdx.x * 64;
  int tid = threadIdx.x, tr = tid >> 4, tc = tid & 15;
  float acc[4][4] = {};
  for (int k0 = 0; k0 < 1024; k0 += 16) {
    for (int i = tid; i < 1024; i += 256) {
      int r = i >> 4, c = i & 15;
      int k = k0 + c;
      const float* src = (k < 256) ? hl : (k < 512) ? h0 : (k < 768) ? hg : h0;
      sA[c][r] = src[(size_t)(bm + r) * 256 + (k & 255)];
    }
    for (int i = tid; i < 1024; i += 256) {
      int kk = i >> 6, j = i & 63;
      int k = k0 + kk;
      const float* Bp = (k < 512) ? (Wl + (size_t)k * 256) : (Wg + (size_t)(k - 512) * 256);
      sB[kk][j] = Bp[bn + j];
    }
    __syncthreads();
#pragma unroll
    for (int kk = 0; kk < 16; kk++) {
      float av[4], bv[4];
#pragma unroll
      for (int i = 0; i < 4; i++) av[i] = sA[kk][tr * 4 + i];
#pragma unroll
      for (int j = 0; j < 4; j++) bv[j] = sB[kk][tc * 4 + j];
#pragma unroll
      for (int i = 0; i < 4; i++)
#pragma unroll
        for (int j = 0; j < 4; j++) acc[i][j] += av[i] * bv[j];
    }
    __syncthreads();
  }
  float omt = 1.f - theta;
#pragma unroll
  for (int i = 0; i < 4; i++) {
    int r = bm + tr * 4 + i;
#pragma unroll
    for (int j = 0; j < 4; j++) {
      int c = bn + tc * 4 + j;
      size_t idx = (size_t)r * 256 + c;
      out[idx] = theta * acc[i][j] + omt * ((1.f - a) * (hl[idx] + hg[idx]) + 2.f * a * h0[idx]);
    }
  }
}

// ---------------- fused edge MLP, MFMA + pipelined staging ----------------
// 32 edges/block. A-staging for chunk c+1 is prefetched into registers while
// chunk c computes (gather latency overlaps MFMA+B-load phase). dmap loads
// nontemporal (streamed once); dmo stores nontemporal (no L2 pollution, keeps
// wb1/wb2 resident for the B-fragment streams).
__global__ __launch_bounds__(256, 3) void k_edge_mlp_mfma(
    const float* __restrict__ xout, const int* __restrict__ adj,
    const float* __restrict__ dmap,
    const float* __restrict__ lin_w, const float* __restrict__ lin_b,
    const unsigned short* __restrict__ wb1, const float* __restrict__ b1,
    const unsigned short* __restrict__ wb2, const float* __restrict__ b2,
    const unsigned short* __restrict__ wb3, const float* __restrict__ b3,
    float* __restrict__ dmo) {
  __shared__ unsigned short sLo[8448];        // sA [32][136] aliased with sT2 [32][264]
  __shared__ unsigned short sT1[32][520];     // 33280 B
  unsigned short (*sA)[136]  = (unsigned short(*)[136])sLo;
  unsigned short (*sT2)[264] = (unsigned short(*)[264])sLo;

  const int tid  = threadIdx.x;
  const int e0   = blockIdx.x * 32;
  const int lane = tid & 63;
  const int wv   = tid >> 6;
  const int r16  = lane & 15;
  const int quad = lane >> 4;

  // staging role: 32 rows x 8 col-groups of 16
  const int sr = tid >> 3;
  const int t8 = tid & 7;
  const int se = e0 + sr;
  const int vsrc = adj[se];
  const int vdst = adj[E_ + se];

  float4 pf0, pf1, pf2, pf3;                  // prefetched xout row segment
  float4 dm0, dm1, dm2, dm3;                  // prefetched dmap row

  // prefetch chunk 0: src node cols [t8*16, t8*16+16)
  {
    const float4* sp = (const float4*)(xout + (size_t)vsrc * D_ + t8 * 16);
    pf0 = sp[0]; pf1 = sp[1]; pf2 = sp[2]; pf3 = sp[3];
  }

  const f32x4 zz = {0.f, 0.f, 0.f, 0.f};
  f32x4 acc1[8][2];
#pragma unroll
  for (int i = 0; i < 8; ++i) { acc1[i][0] = zz; acc1[i][1] = zz; }

  // ---- GEMM1: h3[32,768] @ wb1^T -> t1[32,512], k-chunks of 128, pipelined ----
  for (int c = 0; c < 6; ++c) {
    const int k0 = c * 128;
    __syncthreads();   // prev chunk's sA reads done
    // write prefetched stage data -> sA
    {
      unsigned short tmp[16];
      if (c == 2 || c == 3) {
        int jb = (c - 2) * 128 + t8 * 16;
#pragma unroll
        for (int j = 0; j < 16; ++j) {
          const float4* lw = (const float4*)(lin_w + (size_t)(jb + j) * DIN_);
          float4 w0 = lw[0], w1 = lw[1], w2 = lw[2], w3 = lw[3];
          float acc = lin_b[jb + j];
          acc += dm0.x * w0.x + dm0.y * w0.y + dm0.z * w0.z + dm0.w * w0.w;
          acc += dm1.x * w1.x + dm1.y * w1.y + dm1.z * w1.z + dm1.w * w1.w;
          acc += dm2.x * w2.x + dm2.y * w2.y + dm2.z * w2.z + dm2.w * w2.w;
          acc += dm3.x * w3.x + dm3.y * w3.y + dm3.z * w3.z + dm3.w * w3.w;
          tmp[j] = f2b(acc);
        }
      } else {
        tmp[0]  = f2b(pf0.x); tmp[1]  = f2b(pf0.y); tmp[2]  = f2b(pf0.z); tmp[3]  = f2b(pf0.w);
        tmp[4]  = f2b(pf1.x); tmp[5]  = f2b(pf1.y); tmp[6]  = f2b(pf1.z); tmp[7]  = f2b(pf1.w);
        tmp[8]  = f2b(pf2.x); tmp[9]  = f2b(pf2.y); tmp[10] = f2b(pf2.z); tmp[11] = f2b(pf2.w);
        tmp[12] = f2b(pf3.x); tmp[13] = f2b(pf3.y); tmp[14] = f2b(pf3.z); tmp[15] = f2b(pf3.w);
      }
      unsigned short* dstp = &sA[sr][t8 * 16];
      uint4 q0v = {pack2(tmp[0], tmp[1]),   pack2(tmp[2], tmp[3]),
                   pack2(tmp[4], tmp[5]),   pack2(tmp[6], tmp[7])};
      uint4 q1v = {pack2(tmp[8], tmp[9]),   pack2(tmp[10], tmp[11]),
                   pack2(tmp[12], tmp[13]), pack2(tmp[14], tmp[15])};
      *(uint4*)(dstp) = q0v;
      *(uint4*)(dstp + 8) = q1v;
    }
    // issue prefetch for chunk c+1 (latency overlaps compute below)
    if (c == 0) {
      const float4* sp = (const float4*)(xout + (size_t)vsrc * D_ + 128 + t8 * 16);
      pf0 = sp[0]; pf1 = sp[1]; pf2 = sp[2]; pf3 = sp[3];
    } else if (c == 1) {
      const float4* dp = (const float4*)(dmap + (size_t)se * DIN_);
      dm0 = ntload4(dp); dm1 = ntload4(dp + 1); dm2 = ntload4(dp + 2); dm3 = ntload4(dp + 3);
    } else if (c == 3) {
      const float4* sp = (const float4*)(xout + (size_t)vdst * D_ + t8 * 16);
      pf0 = sp[0]; pf1 = sp[1]; pf2 = sp[2]; pf3 = sp[3];
    } else if (c == 4) {
      const float4* sp = (const float4*)(xout + (size_t)vdst * D_ + 128 + t8 * 16);
      pf0 = sp[0]; pf1 = sp[1]; pf2 = sp[2]; pf3 = sp[3];
    }
    __syncthreads();
    // compute chunk c
#pragma unroll
    for (int kk = 0; kk < 4; ++kk) {
      bf16_8 a0 = frag16(&sA[r16][kk * 32 + quad * 8]);
      bf16_8 a1 = frag16(&sA[16 + r16][kk * 32 + quad * 8]);
#pragma unroll
      for (int i = 0; i < 8; ++i) {
        const unsigned short* bp =
            wb1 + (size_t)(wv * 128 + i * 16 + r16) * 768 + k0 + kk * 32 + quad * 8;
        bf16_8 bf = frag16(bp);
        acc1[i][0] = __builtin_amdgcn_mfma_f32_16x16x32_bf16(a0, bf, acc1[i][0], 0, 0, 0);
        acc1[i][1] = __builtin_amdgcn_mfma_f32_16x16x32_bf16(a1, bf, acc1[i][1], 0, 0, 0);
      }
    }
  }
  // epilogue 1: bias + gelu -> sT1 (bf16)
#pragma unroll
  for (int i = 0; i < 8; ++i) {
    int col = wv * 128 + i * 16 + r16;
    float bb = b1[col];
#pragma unroll
    for (int m = 0; m < 2; ++m)
#pragma unroll
      for (int r = 0; r < 4; ++r) {
        int row = m * 16 + quad * 4 + r;
        sT1[row][col] = f2b(gelu_exact(acc1[i][m][r] + bb));
      }
  }
  __syncthreads();

  // ---- GEMM2: t1[32,512] @ wb2^T -> t2[32,256] ----
  f32x4 acc2[4][2];
#pragma unroll
  for (int i = 0; i < 4; ++i) { acc2[i][0] = zz; acc2[i][1] = zz; }
#pragma unroll 4
  for (int ks = 0; ks < 16; ++ks) {
    bf16_8 a0 = frag16(&sT1[r16][ks * 32 + quad * 8]);
    bf16_8 a1 = frag16(&sT1[16 + r16][ks * 32 + quad * 8]);
#pragma unroll
    for (int i = 0; i < 4; ++i) {
      const unsigned short* bp =
          wb2 + (size_t)(wv * 64 + i * 16 + r16) * 512 + ks * 32 + quad * 8;
      bf16_8 bf = frag16(bp);
      acc2[i][0] = __builtin_amdgcn_mfma_f32_16x16x32_bf16(a0, bf, acc2[i][0], 0, 0, 0);
      acc2[i][1] = __builtin_amdgcn_mfma_f32_16x16x32_bf16(a1, bf, acc2[i][1], 0, 0, 0);
    }
  }
  // epilogue 2: bias + gelu -> sT2 (aliases sA; all sA reads completed pre-barrier)
#pragma unroll
  for (int i = 0; i < 4; ++i) {
    int col = wv * 64 + i * 16 + r16;
    float bb = b2[col];
#pragma unroll
    for (int m = 0; m < 2; ++m)
#pragma unroll
      for (int r = 0; r < 4; ++r) {
        int row = m * 16 + quad * 4 + r;
        sT2[row][col] = f2b(gelu_exact(acc2[i][m][r] + bb));
      }
  }
  __syncthreads();

  // ---- GEMM3: t2[32,256] @ wb3^T -> dm_out[32,16] ----
  if (wv < 2) {
    f32x4 acc3 = zz;
#pragma unroll
    for (int ks = 0; ks < 8; ++ks) {
      bf16_8 a = frag16(&sT2[wv * 16 + r16][ks * 32 + quad * 8]);
      bf16_8 b = frag16(wb3 + (size_t)r16 * 256 + ks * 32 + quad * 8);
      acc3 = __builtin_amdgcn_mfma_f32_16x16x32_bf16(a, b, acc3, 0, 0, 0);
    }
    float bb = b3[r16];
#pragma unroll
    for (int r = 0; r < 4; ++r) {
      int row = wv * 16 + quad * 4 + r;
      __builtin_nontemporal_store(acc3[r] + bb, &dmo[(size_t)(e0 + row) * DIN_ + r16]);
    }
  }
}

extern "C" void kernel_launch(void* const* d_in, const int* in_sizes, int n_in,
                              void* d_out, int out_size, void* d_ws, size_t ws_size,
                              hipStream_t stream) {
  const float* input = (const float*)d_in[0];
  const int*   adj   = (const int*)d_in[1];
  const float* h0    = (const float*)d_in[2];
  const void*  lamda = d_in[3];
  const float* alpha = (const float*)d_in[4];
  const void*  lll   = d_in[5];
  const float* dmap  = (const float*)d_in[6];
  const float* nrm   = (const float*)d_in[7];
  const float* Wl    = (const float*)d_in[8];
  const float* Wg    = (const float*)d_in[9];
  const float* lin_w = (const float*)d_in[10];
  const float* lin_b = (const float*)d_in[11];
  const float* w1    = (const float*)d_in[12];
  const float* b1    = (const float*)d_in[13];
  const float* w2    = (const float*)d_in[14];
  const float* b2    = (const float*)d_in[15];
  const float* w3    = (const float*)d_in[16];
  const float* b3    = (const float*)d_in[17];
  const float* ipw   = (const float*)d_in[18];
  const float* ipb   = (const float*)d_in[19];
  const float* opw   = (const float*)d_in[20];
  const float* opb   = (const float*)d_in[21];
  float* out = (float*)d_out;

  float* ws   = (float*)d_ws;
  float* xout = ws;                               // N*D f32
  float* qkv  = xout + (size_t)N_ * D_;           // N*3D f32
  float* atto = qkv  + (size_t)N_ * 3 * D_;       // N*D f32
  float* hgl  = atto + (size_t)N_ * D_;           // N*D f32
  unsigned short* wb1 = (unsigned short*)(hgl + (size_t)N_ * D_);  // 512*768
  unsigned short* wb2 = wb1 + 512 * 768;          // 256*512
  unsigned short* wb3 = wb2 + 256 * 512;          // 16*256
  unsigned short* Qb  = wb3 + 16 * 256;           // 2*N*128
  unsigned short* Kb  = Qb + 2 * N_ * HD_;        // 2*N*128
  unsigned short* Vt  = Kb + 2 * N_ * HD_;        // 2*128*N
  // total ~32.5 MB of ws

  // bf16 weight conversion (native [out,in] layout == MFMA B-frag layout)
  k_f2b<<<dim3((512 * 768 + 255) / 256), 256, 0, stream>>>(w1, wb1, 512 * 768);
  k_f2b<<<dim3((256 * 512 + 255) / 256), 256, 0, stream>>>(w2, wb2, 256 * 512);
  k_f2b<<<dim3((16 * 256 + 255) / 256), 256, 0, stream>>>(w3, wb3, 16 * 256);

  // x_out = input, then scatter-add messages
  k_copy4<<<dim3(N_ * D_ / 4 / 256), 256, 0, stream>>>((const float4*)input, (float4*)xout,
                                                       N_ * D_ / 4);
  k_scatter<<<dim3(E_ / 4), 256, 0, stream>>>(input, adj, dmap, nrm, lin_w, lin_b, xout);

  // MHA: qkv proj -> bf16 split/transpose -> MFMA flash attention -> out_proj
  k_gemm_bt<<<dim3(D3_ / 64, N_ / 64), 256, 0, stream>>>(input, ipw, ipb, qkv, N_, D3_, D_);
  k_qk2b<<<dim3(N_ * 512 / 8 / 256), 256, 0, stream>>>(qkv, Qb, Kb);
  k_v2t<<<dim3(N_ / 64, 2), 256, 0, stream>>>(qkv, Vt);
  k_attn_mfma<<<dim3(N_ / 16, 2), 256, 0, stream>>>(Qb, Kb, Vt, atto);
  k_gemm_bt<<<dim3(D_ / 64, N_ / 64), 256, 0, stream>>>(atto, opw, opb, hgl, N_, D_, D_);

  // output[N,D]
  k_final<<<dim3(4, N_ / 64), 256, 0, stream>>>(xout, hgl, h0, Wl, Wg, alpha, lamda, lll, out);

  // dm_out[E,16]
  k_edge_mlp_mfma<<<dim3(E_ / 32), 256, 0, stream>>>(xout, adj, dmap, lin_w, lin_b,
                                                     wb1, b1, wb2, b2, wb3, b3,
                                                     out + (size_t)N_ * D_);
}

// Round 5
// 1497.165 us; speedup vs baseline: 2.7720x; 1.1449x over previous
//
#include <hip/hip_runtime.h>
#include <hip/hip_bf16.h>
#include <math.h>

// Problem constants
constexpr int N_   = 4096;
constexpr int E_   = 131072;
constexpr int D_   = 256;
constexpr int DIN_ = 16;
constexpr int D3_  = 768;   // 3*D
constexpr int HD_  = 128;   // head dim

typedef __bf16 bf16_8 __attribute__((ext_vector_type(8)));
typedef float  f32x4  __attribute__((ext_vector_type(4)));
typedef float  f32x4v __attribute__((ext_vector_type(4)));

// ---- bf16 helpers ----
__device__ __forceinline__ unsigned short f2b(float f) {
  unsigned int u = __float_as_uint(f);
  u = u + 0x7fffu + ((u >> 16) & 1u);   // round-to-nearest-even
  return (unsigned short)(u >> 16);
}
__device__ __forceinline__ float b2f(unsigned short s) {
  return __uint_as_float(((unsigned int)s) << 16);
}
__device__ __forceinline__ unsigned int pack2(unsigned short lo, unsigned short hi) {
  return (unsigned int)lo | ((unsigned int)hi << 16);
}
__device__ __forceinline__ bf16_8 frag16(const unsigned short* p) {
  uint4 v = *(const uint4*)p;           // 16B load (LDS b128 or global dwordx4)
  return __builtin_bit_cast(bf16_8, v);
}
__device__ __forceinline__ float4 ntload4(const void* p) {
  f32x4v v = __builtin_nontemporal_load((const f32x4v*)p);
  float4 r;
  r.x = v[0]; r.y = v[1]; r.z = v[2]; r.w = v[3];
  return r;
}

// Python scalar may arrive as int32 or float32 bits; values here are small ints.
__device__ __forceinline__ float scalar_as_float(const void* p) {
  int iv = *(const int*)p;
  if (iv >= 1 && iv <= 1000000) return (float)iv;  // plausible int
  return __int_as_float(iv);                       // else float bits
}

__device__ __forceinline__ float gelu_exact(float v) {
  return 0.5f * v * (1.0f + erff(v * 0.70710678118654752f));
}

// ---------------- f32 -> bf16 convert ----------------
__global__ void k_f2b(const float* __restrict__ src, unsigned short* __restrict__ dst, int n) {
  int i = blockIdx.x * 256 + threadIdx.x;
  if (i < n) dst[i] = f2b(src[i]);
}

// ---------------- copy (float4) ----------------
__global__ void k_copy4(const float4* __restrict__ src, float4* __restrict__ dst, int n4) {
  int idx = blockIdx.x * 256 + threadIdx.x;
  if (idx < n4) dst[idx] = src[idx];
}

// ---------------- edge_attr precompute: eab16[E,256] = bf16(dmap@lin_w^T+lin_b) ----------------
__global__ __launch_bounds__(256) void k_edge_attr(
    const float* __restrict__ dmap, const float* __restrict__ lin_w,
    const float* __restrict__ lin_b, unsigned short* __restrict__ eab) {
  __shared__ float sdm[16][17];
  int tid = threadIdx.x;
  int e0 = blockIdx.x * 16;
  int el = tid >> 4, jg = tid & 15;
  sdm[el][jg] = dmap[(size_t)(e0 + el) * DIN_ + jg];
  __syncthreads();
  float dm[DIN_];
#pragma unroll
  for (int k = 0; k < DIN_; ++k) dm[k] = sdm[el][k];
  unsigned int pk[8];
#pragma unroll
  for (int j2 = 0; j2 < 8; ++j2) {
    unsigned short o2[2];
#pragma unroll
    for (int s = 0; s < 2; ++s) {
      int col = jg * 16 + j2 * 2 + s;
      const float4* lw = (const float4*)(lin_w + (size_t)col * DIN_);
      float4 w0 = lw[0], w1 = lw[1], w2 = lw[2], w3 = lw[3];
      float acc = lin_b[col];
      acc += dm[0] * w0.x + dm[1] * w0.y + dm[2] * w0.z + dm[3] * w0.w;
      acc += dm[4] * w1.x + dm[5] * w1.y + dm[6] * w1.z + dm[7] * w1.w;
      acc += dm[8] * w2.x + dm[9] * w2.y + dm[10] * w2.z + dm[11] * w2.w;
      acc += dm[12] * w3.x + dm[13] * w3.y + dm[14] * w3.z + dm[15] * w3.w;
      o2[s] = f2b(acc);
    }
    pk[j2] = pack2(o2[0], o2[1]);
  }
  uint4* dst = (uint4*)(eab + (size_t)(e0 + el) * D_ + jg * 16);
  dst[0] = make_uint4(pk[0], pk[1], pk[2], pk[3]);
  dst[1] = make_uint4(pk[4], pk[5], pk[6], pk[7]);
}

// ---------------- scatter using precomputed edge_attr ----------------
__global__ __launch_bounds__(256) void k_scatter_ea(
    const float* __restrict__ x, const int* __restrict__ adj,
    const unsigned short* __restrict__ eab, const float* __restrict__ nrm,
    float* __restrict__ xout) {
  int te = threadIdx.x >> 6;
  int d4 = threadIdx.x & 63;
  int e  = blockIdx.x * 4 + te;
  int vs = adj[e];
  int vd = adj[E_ + e];
  float w = nrm[e];
  int d = d4 * 4;
  float4 xs = *(const float4*)(x + (size_t)vs * D_ + d);
  uint2 ep = *(const uint2*)(eab + (size_t)e * D_ + d);
  float* op = xout + (size_t)vd * D_ + d;
  atomicAdd(op + 0, w * (xs.x + b2f((unsigned short)(ep.x & 0xffff))));
  atomicAdd(op + 1, w * (xs.y + b2f((unsigned short)(ep.x >> 16))));
  atomicAdd(op + 2, w * (xs.z + b2f((unsigned short)(ep.y & 0xffff))));
  atomicAdd(op + 3, w * (xs.w + b2f((unsigned short)(ep.y >> 16))));
}

// ---------------- legacy scatter (fallback path) ----------------
__global__ __launch_bounds__(256) void k_scatter(
    const float* __restrict__ x, const int* __restrict__ adj,
    const float* __restrict__ dmap, const float* __restrict__ nrm,
    const float* __restrict__ lin_w, const float* __restrict__ lin_b,
    float* __restrict__ xout) {
  __shared__ float s_dm[4][DIN_];
  int te = threadIdx.x >> 6;
  int d4 = threadIdx.x & 63;
  int e  = blockIdx.x * 4 + te;
  if (d4 < DIN_) s_dm[te][d4] = dmap[(size_t)e * DIN_ + d4];
  __syncthreads();
  int vs = adj[e];
  int vd = adj[E_ + e];
  float w = nrm[e];
  int d = d4 * 4;
  float4 xs = *(const float4*)(x + (size_t)vs * D_ + d);
  float ea[4];
#pragma unroll
  for (int q = 0; q < 4; q++) {
    const float* lw = lin_w + (size_t)(d + q) * DIN_;
    float acc = lin_b[d + q];
#pragma unroll
    for (int k = 0; k < DIN_; k++) acc += s_dm[te][k] * lw[k];
    ea[q] = acc;
  }
  float* op = xout + (size_t)vd * D_ + d;
  atomicAdd(op + 0, w * (xs.x + ea[0]));
  atomicAdd(op + 1, w * (xs.y + ea[1]));
  atomicAdd(op + 2, w * (xs.z + ea[2]));
  atomicAdd(op + 3, w * (xs.w + ea[3]));
}

// ---------------- C[M,N] = A[M,K] @ B[N,K]^T + bias ----------------
__global__ __launch_bounds__(256) void k_gemm_bt(
    const float* __restrict__ A, const float* __restrict__ B,
    const float* __restrict__ bias, float* __restrict__ C,
    int M, int Nn, int K) {
  __shared__ float sA[16][68];
  __shared__ float sB[16][68];
  int bm = blockIdx.y * 64, bn = blockIdx.x * 64;
  int tid = threadIdx.x;
  int tr = tid >> 4, tc = tid & 15;
  float acc[4][4] = {};
  for (int k0 = 0; k0 < K; k0 += 16) {
    for (int i = tid; i < 1024; i += 256) {
      int r = i >> 4, c = i & 15;
      sA[c][r] = A[(size_t)(bm + r) * K + k0 + c];
      sB[c][r] = B[(size_t)(bn + r) * K + k0 + c];
    }
    __syncthreads();
#pragma unroll
    for (int kk = 0; kk < 16; kk++) {
      float av[4], bv[4];
#pragma unroll
      for (int i = 0; i < 4; i++) av[i] = sA[kk][tr * 4 + i];
#pragma unroll
      for (int j = 0; j < 4; j++) bv[j] = sB[kk][tc * 4 + j];
#pragma unroll
      for (int i = 0; i < 4; i++)
#pragma unroll
        for (int j = 0; j < 4; j++) acc[i][j] += av[i] * bv[j];
    }
    __syncthreads();
  }
#pragma unroll
  for (int i = 0; i < 4; i++) {
    int r = bm + tr * 4 + i;
#pragma unroll
    for (int j = 0; j < 4; j++) {
      int c = bn + tc * 4 + j;
      C[(size_t)r * Nn + c] = acc[i][j] + bias[c];
    }
  }
}

// ---------------- qkv split: fp32 [N,768] -> bf16 Qb/Kb [h][n][128] ----------------
__global__ void k_qk2b(const float* __restrict__ qkv,
                       unsigned short* __restrict__ Qb, unsigned short* __restrict__ Kb) {
  int off = (blockIdx.x * 256 + threadIdx.x) * 8;   // over N*512
  int n = off >> 9, c = off & 511;
  const float* src = qkv + (size_t)n * D3_ + c;     // Q cols 0..255, K cols 256..511
  float4 a = *(const float4*)src;
  float4 b = *(const float4*)(src + 4);
  uint4 p = {pack2(f2b(a.x), f2b(a.y)), pack2(f2b(a.z), f2b(a.w)),
             pack2(f2b(b.x), f2b(b.y)), pack2(f2b(b.z), f2b(b.w))};
  int cc = c & 255;
  int hh = cc >> 7, d = cc & 127;
  unsigned short* dst = (c < 256 ? Qb : Kb) + (size_t)hh * N_ * HD_ + (size_t)n * HD_ + d;
  *(uint4*)dst = p;
}

// ---------------- V transpose: fp32 qkv V-cols -> bf16 Vt [h][128][N] ----------------
__global__ __launch_bounds__(256) void k_v2t(const float* __restrict__ qkv,
                                             unsigned short* __restrict__ Vt) {
  __shared__ unsigned short sv[64][136];
  int h = blockIdx.y;
  int n0 = blockIdx.x * 64;
  int tid = threadIdx.x;
#pragma unroll
  for (int it = 0; it < 4; ++it) {
    int off = (tid + it * 256) * 8;
    int r = off >> 7, d = off & 127;
    const float* src = qkv + (size_t)(n0 + r) * D3_ + 2 * D_ + h * HD_ + d;
    float4 a = *(const float4*)src;
    float4 b = *(const float4*)(src + 4);
    uint4 p = {pack2(f2b(a.x), f2b(a.y)), pack2(f2b(a.z), f2b(a.w)),
               pack2(f2b(b.x), f2b(b.y)), pack2(f2b(b.z), f2b(b.w))};
    *(uint4*)&sv[r][d] = p;
  }
  __syncthreads();
#pragma unroll
  for (int it = 0; it < 4; ++it) {
    int off = (tid + it * 256) * 8;
    int d = off >> 6, k = off & 63;
    unsigned short t[8];
#pragma unroll
    for (int j = 0; j < 8; ++j) t[j] = sv[k + j][d];
    uint4 p = {pack2(t[0], t[1]), pack2(t[2], t[3]),
               pack2(t[4], t[5]), pack2(t[6], t[7])};
    *(uint4*)(Vt + (size_t)h * HD_ * N_ + (size_t)d * N_ + n0 + k) = p;
  }
}

// ---------------- MFMA flash attention, H=2, HD=128 ----------------
__global__ __launch_bounds__(256) void k_attn_mfma(
    const unsigned short* __restrict__ Qb, const unsigned short* __restrict__ Kb,
    const unsigned short* __restrict__ Vt, float* __restrict__ o_out) {
  __shared__ unsigned short sK[64][136];   // keys x dims (+8 pad)
  __shared__ unsigned short sV[128][72];   // dims x keys (+8 pad)
  __shared__ float          sS[16][68];    // scores
  __shared__ unsigned short sP[16][72];    // probs bf16 (A-frag layout)
  __shared__ float sm[16], sl[16], sa[16];

  const int tid  = threadIdx.x;
  const int h    = blockIdx.y;
  const int q0   = blockIdx.x * 16;
  const int lane = tid & 63;
  const int wv   = tid >> 6;
  const int r16  = lane & 15;
  const int quad = lane >> 4;

  bf16_8 qf[4];
#pragma unroll
  for (int kk = 0; kk < 4; ++kk)
    qf[kk] = frag16(Qb + (size_t)h * N_ * HD_ + (size_t)(q0 + r16) * HD_ + kk * 32 + quad * 8);

  if (tid < 16) { sm[tid] = -1e30f; sl[tid] = 0.f; }

  const f32x4 zz = {0.f, 0.f, 0.f, 0.f};
  f32x4 o0 = zz, o1 = zz;

  const unsigned short* Kh = Kb + (size_t)h * N_ * HD_;
  const unsigned short* Vh = Vt + (size_t)h * HD_ * N_;

  for (int c0 = 0; c0 < N_; c0 += 64) {
    __syncthreads();
#pragma unroll
    for (int it = 0; it < 4; ++it) {
      int off = (tid + it * 256) * 8;
      int key = off >> 7, d = off & 127;
      *(uint4*)&sK[key][d] = *(const uint4*)(Kh + (size_t)(c0 + key) * HD_ + d);
    }
#pragma unroll
    for (int it = 0; it < 4; ++it) {
      int off = (tid + it * 256) * 8;
      int d = off >> 6, k = off & 63;
      *(uint4*)&sV[d][k] = *(const uint4*)(Vh + (size_t)d * N_ + c0 + k);
    }
    __syncthreads();
    f32x4 s = zz;
#pragma unroll
    for (int kk = 0; kk < 4; ++kk) {
      bf16_8 bf = frag16(&sK[wv * 16 + r16][kk * 32 + quad * 8]);
      s = __builtin_amdgcn_mfma_f32_16x16x32_bf16(qf[kk], bf, s, 0, 0, 0);
    }
    const float sc = 0.08838834764831845f;   // 1/sqrt(128)
#pragma unroll
    for (int r = 0; r < 4; ++r)
      sS[quad * 4 + r][wv * 16 + r16] = s[r] * sc;
    __syncthreads();
    {
      int row = tid >> 4, i = tid & 15;
      float4 v = *(const float4*)&sS[row][i * 4];
      float mx = fmaxf(fmaxf(v.x, v.y), fmaxf(v.z, v.w));
#pragma unroll
      for (int m = 1; m <= 8; m <<= 1) mx = fmaxf(mx, __shfl_xor(mx, m));
      float mo = sm[row];
      float mn = fmaxf(mo, mx);
      float p0 = __expf(v.x - mn), p1 = __expf(v.y - mn);
      float p2 = __expf(v.z - mn), p3 = __expf(v.w - mn);
      float ps = p0 + p1 + p2 + p3;
#pragma unroll
      for (int m = 1; m <= 8; m <<= 1) ps += __shfl_xor(ps, m);
      uint2 pk = {pack2(f2b(p0), f2b(p1)), pack2(f2b(p2), f2b(p3))};
      *(uint2*)&sP[row][i * 4] = pk;
      if (i == 0) {
        float al = __expf(mo - mn);
        sl[row] = sl[row] * al + ps;
        sm[row] = mn;
        sa[row] = al;
      }
    }
    __syncthreads();
    {
      float al0 = sa[quad * 4 + 0], al1 = sa[quad * 4 + 1];
      float al2 = sa[quad * 4 + 2], al3 = sa[quad * 4 + 3];
      o0[0] *= al0; o0[1] *= al1; o0[2] *= al2; o0[3] *= al3;
      o1[0] *= al0; o1[1] *= al1; o1[2] *= al2; o1[3] *= al3;
#pragma unroll
      for (int kk = 0; kk < 2; ++kk) {
        bf16_8 pa = frag16(&sP[r16][kk * 32 + quad * 8]);
        bf16_8 v0 = frag16(&sV[wv * 32 + r16][kk * 32 + quad * 8]);
        bf16_8 v1 = frag16(&sV[wv * 32 + 16 + r16][kk * 32 + quad * 8]);
        o0 = __builtin_amdgcn_mfma_f32_16x16x32_bf16(pa, v0, o0, 0, 0, 0);
        o1 = __builtin_amdgcn_mfma_f32_16x16x32_bf16(pa, v1, o1, 0, 0, 0);
      }
    }
  }
  {
    float i0 = 1.f / sl[quad * 4 + 0], i1 = 1.f / sl[quad * 4 + 1];
    float i2 = 1.f / sl[quad * 4 + 2], i3 = 1.f / sl[quad * 4 + 3];
    float* base = o_out + (size_t)q0 * D_ + h * HD_ + wv * 32 + r16;
    base[(size_t)(quad * 4 + 0) * D_] = o0[0] * i0;
    base[(size_t)(quad * 4 + 1) * D_] = o0[1] * i1;
    base[(size_t)(quad * 4 + 2) * D_] = o0[2] * i2;
    base[(size_t)(quad * 4 + 3) * D_] = o0[3] * i3;
    float* base1 = base + 16;
    base1[(size_t)(quad * 4 + 0) * D_] = o1[0] * i0;
    base1[(size_t)(quad * 4 + 1) * D_] = o1[1] * i1;
    base1[(size_t)(quad * 4 + 2) * D_] = o1[2] * i2;
    base1[(size_t)(quad * 4 + 3) * D_] = o1[3] * i3;
  }
}

// ---------------- final combine ----------------
__global__ __launch_bounds__(256) void k_final(
    const float* __restrict__ hl, const float* __restrict__ hg, const float* __restrict__ h0,
    const float* __restrict__ Wl, const float* __restrict__ Wg,
    const float* __restrict__ alpha_p, const void* lamda_p, const void* l_p,
    float* __restrict__ out) {
  __shared__ float sA[16][68];
  __shared__ float sB[16][68];
  float theta = fminf(1.f, logf(scalar_as_float(lamda_p) / scalar_as_float(l_p) + 1.f));
  float a = alpha_p[0];
  int bm = blockIdx.y * 64, bn = blockIdx.x * 64;
  int tid = threadIdx.x, tr = tid >> 4, tc = tid & 15;
  float acc[4][4] = {};
  for (int k0 = 0; k0 < 1024; k0 += 16) {
    for (int i = tid; i < 1024; i += 256) {
      int r = i >> 4, c = i & 15;
      int k = k0 + c;
      const float* src = (k < 256) ? hl : (k < 512) ? h0 : (k < 768) ? hg : h0;
      sA[c][r] = src[(size_t)(bm + r) * 256 + (k & 255)];
    }
    for (int i = tid; i < 1024; i += 256) {
      int kk = i >> 6, j = i & 63;
      int k = k0 + kk;
      const float* Bp = (k < 512) ? (Wl + (size_t)k * 256) : (Wg + (size_t)(k - 512) * 256);
      sB[kk][j] = Bp[bn + j];
    }
    __syncthreads();
#pragma unroll
    for (int kk = 0; kk < 16; kk++) {
      float av[4], bv[4];
#pragma unroll
      for (int i = 0; i < 4; i++) av[i] = sA[kk][tr * 4 + i];
#pragma unroll
      for (int j = 0; j < 4; j++) bv[j] = sB[kk][tc * 4 + j];
#pragma unroll
      for (int i = 0; i < 4; i++)
#pragma unroll
        for (int j = 0; j < 4; j++) acc[i][j] += av[i] * bv[j];
    }
    __syncthreads();
  }
  float omt = 1.f - theta;
#pragma unroll
  for (int i = 0; i < 4; i++) {
    int r = bm + tr * 4 + i;
#pragma unroll
    for (int j = 0; j < 4; j++) {
      int c = bn + tc * 4 + j;
      size_t idx = (size_t)r * 256 + c;
      out[idx] = theta * acc[i][j] + omt * ((1.f - a) * (hl[idx] + hg[idx]) + 2.f * a * h0[idx]);
    }
  }
}

// ================= edge MLP as tiled GEMMs (fast path) =================
// GEMM1: h3[E,768] @ wb1^T -> gelu -> t1[E,512] bf16.  128x128 tile, BK=64.
// A rows gathered on the fly (xout[src] | eab | xout[dst]); B = wb1 rows.
// Padded LDS [128][72] for both operands -> conflict-free b128 frag reads.
__global__ __launch_bounds__(256) void k_mlp_gemm1(
    const float* __restrict__ xout, const int* __restrict__ adj,
    const unsigned short* __restrict__ eab, const unsigned short* __restrict__ wb1,
    const float* __restrict__ b1, unsigned short* __restrict__ t1) {
  __shared__ unsigned short sA[128][72];   // 18432 B
  __shared__ unsigned short sB[128][72];   // 18432 B
  const int tid  = threadIdx.x;
  const int e0   = blockIdx.x * 128;
  const int j0   = blockIdx.y * 128;
  const int lane = tid & 63, wv = tid >> 6;
  const int r16  = lane & 15, quad = lane >> 4;
  const int sr   = tid >> 1;            // staged row 0..127
  const int sh   = (tid & 1) * 32;      // col half (elems)
  const int vsrc = adj[e0 + sr];
  const int vdst = adj[E_ + e0 + sr];

  const f32x4 zz = {0.f, 0.f, 0.f, 0.f};
  f32x4 acc[2][8];
#pragma unroll
  for (int m = 0; m < 2; ++m)
#pragma unroll
    for (int n = 0; n < 8; ++n) acc[m][n] = zz;

  for (int ki = 0; ki < 12; ++ki) {
    const int k0 = ki * 64;
    __syncthreads();
    // ---- stage A: row sr, cols [k0+sh, k0+sh+32) of the 768-wide h3 ----
    {
      const int gc = k0 + sh;
      uint4* dst = (uint4*)&sA[sr][sh];
      if (gc < 256 || gc >= 512) {
        const int node = (gc < 256) ? vsrc : vdst;
        const float4* src = (const float4*)(xout + (size_t)node * D_ + (gc & 255));
        unsigned int pk[16];
#pragma unroll
        for (int q = 0; q < 8; ++q) {
          float4 v = src[q];
          pk[2 * q]     = pack2(f2b(v.x), f2b(v.y));
          pk[2 * q + 1] = pack2(f2b(v.z), f2b(v.w));
        }
#pragma unroll
        for (int i = 0; i < 4; ++i)
          dst[i] = make_uint4(pk[4 * i], pk[4 * i + 1], pk[4 * i + 2], pk[4 * i + 3]);
      } else {
        const uint4* src = (const uint4*)(eab + (size_t)(e0 + sr) * D_ + (gc - 256));
#pragma unroll
        for (int i = 0; i < 4; ++i) dst[i] = src[i];
      }
    }
    // ---- stage B: wb1 row j0+sr, same col chunk ----
    {
      const uint4* src = (const uint4*)(wb1 + (size_t)(j0 + sr) * 768 + k0 + sh);
      uint4* dst = (uint4*)&sB[sr][sh];
#pragma unroll
      for (int i = 0; i < 4; ++i) dst[i] = src[i];
    }
    __syncthreads();
    // ---- compute ----
#pragma unroll
    for (int kk = 0; kk < 2; ++kk) {
      bf16_8 a0 = frag16(&sA[wv * 32 + r16][kk * 32 + quad * 8]);
      bf16_8 a1 = frag16(&sA[wv * 32 + 16 + r16][kk * 32 + quad * 8]);
#pragma unroll
      for (int n = 0; n < 8; ++n) {
        bf16_8 bf = frag16(&sB[n * 16 + r16][kk * 32 + quad * 8]);
        acc[0][n] = __builtin_amdgcn_mfma_f32_16x16x32_bf16(a0, bf, acc[0][n], 0, 0, 0);
        acc[1][n] = __builtin_amdgcn_mfma_f32_16x16x32_bf16(a1, bf, acc[1][n], 0, 0, 0);
      }
    }
  }
  // ---- epilogue: bias + gelu -> t1 bf16 ----
  float bias[8];
#pragma unroll
  for (int n = 0; n < 8; ++n) bias[n] = b1[j0 + n * 16 + r16];
#pragma unroll
  for (int m = 0; m < 2; ++m)
#pragma unroll
    for (int n = 0; n < 8; ++n)
#pragma unroll
      for (int rg = 0; rg < 4; ++rg) {
        int row = e0 + wv * 32 + m * 16 + quad * 4 + rg;
        int col = j0 + n * 16 + r16;
        t1[(size_t)row * 512 + col] = f2b(gelu_exact(acc[m][n][rg] + bias[n]));
      }
}

// GEMM2: t1[E,512] @ wb2^T -> gelu -> t2[E,256] bf16.  Same tile structure.
__global__ __launch_bounds__(256) void k_mlp_gemm2(
    const unsigned short* __restrict__ t1, const unsigned short* __restrict__ wb2,
    const float* __restrict__ b2, unsigned short* __restrict__ t2) {
  __shared__ unsigned short sA[128][72];
  __shared__ unsigned short sB[128][72];
  const int tid  = threadIdx.x;
  const int e0   = blockIdx.x * 128;
  const int j0   = blockIdx.y * 128;
  const int lane = tid & 63, wv = tid >> 6;
  const int r16  = lane & 15, quad = lane >> 4;
  const int sr   = tid >> 1;
  const int sh   = (tid & 1) * 32;

  const f32x4 zz = {0.f, 0.f, 0.f, 0.f};
  f32x4 acc[2][8];
#pragma unroll
  for (int m = 0; m < 2; ++m)
#pragma unroll
    for (int n = 0; n < 8; ++n) acc[m][n] = zz;

  for (int ki = 0; ki < 8; ++ki) {
    const int k0 = ki * 64;
    __syncthreads();
    {
      const uint4* src = (const uint4*)(t1 + (size_t)(e0 + sr) * 512 + k0 + sh);
      uint4* dst = (uint4*)&sA[sr][sh];
#pragma unroll
      for (int i = 0; i < 4; ++i) dst[i] = src[i];
    }
    {
      const uint4* src = (const uint4*)(wb2 + (size_t)(j0 + sr) * 512 + k0 + sh);
      uint4* dst = (uint4*)&sB[sr][sh];
#pragma unroll
      for (int i = 0; i < 4; ++i) dst[i] = src[i];
    }
    __syncthreads();
#pragma unroll
    for (int kk = 0; kk < 2; ++kk) {
      bf16_8 a0 = frag16(&sA[wv * 32 + r16][kk * 32 + quad * 8]);
      bf16_8 a1 = frag16(&sA[wv * 32 + 16 + r16][kk * 32 + quad * 8]);
#pragma unroll
      for (int n = 0; n < 8; ++n) {
        bf16_8 bf = frag16(&sB[n * 16 + r16][kk * 32 + quad * 8]);
        acc[0][n] = __builtin_amdgcn_mfma_f32_16x16x32_bf16(a0, bf, acc[0][n], 0, 0, 0);
        acc[1][n] = __builtin_amdgcn_mfma_f32_16x16x32_bf16(a1, bf, acc[1][n], 0, 0, 0);
      }
    }
  }
  float bias[8];
#pragma unroll
  for (int n = 0; n < 8; ++n) bias[n] = b2[j0 + n * 16 + r16];
#pragma unroll
  for (int m = 0; m < 2; ++m)
#pragma unroll
    for (int n = 0; n < 8; ++n)
#pragma unroll
      for (int rg = 0; rg < 4; ++rg) {
        int row = e0 + wv * 32 + m * 16 + quad * 4 + rg;
        int col = j0 + n * 16 + r16;
        t2[(size_t)row * 256 + col] = f2b(gelu_exact(acc[m][n][rg] + bias[n]));
      }
}

// GEMM3: t2[E,256] @ wb3^T + b3 -> dm_out[E,16].  64 edges/block, 16/wave.
__global__ __launch_bounds__(256) void k_mlp_gemm3(
    const unsigned short* __restrict__ t2, const unsigned short* __restrict__ wb3,
    const float* __restrict__ b3, float* __restrict__ dmo) {
  const int tid  = threadIdx.x;
  const int lane = tid & 63, wv = tid >> 6;
  const int r16  = lane & 15, quad = lane >> 4;
  const int eb   = blockIdx.x * 64 + wv * 16;
  const f32x4 zz = {0.f, 0.f, 0.f, 0.f};
  f32x4 acc = zz;
#pragma unroll
  for (int ks = 0; ks < 8; ++ks) {
    bf16_8 a = frag16(t2 + (size_t)(eb + r16) * 256 + ks * 32 + quad * 8);
    bf16_8 b = frag16(wb3 + (size_t)r16 * 256 + ks * 32 + quad * 8);
    acc = __builtin_amdgcn_mfma_f32_16x16x32_bf16(a, b, acc, 0, 0, 0);
  }
  float bb = b3[r16];
#pragma unroll
  for (int rg = 0; rg < 4; ++rg)
    dmo[(size_t)(eb + quad * 4 + rg) * DIN_ + r16] = acc[rg] + bb;
}

// ---------------- fused edge MLP (fallback path, R4 version) ----------------
__global__ __launch_bounds__(256, 3) void k_edge_mlp_mfma(
    const float* __restrict__ xout, const int* __restrict__ adj,
    const float* __restrict__ dmap,
    const float* __restrict__ lin_w, const float* __restrict__ lin_b,
    const unsigned short* __restrict__ wb1, const float* __restrict__ b1,
    const unsigned short* __restrict__ wb2, const float* __restrict__ b2,
    const unsigned short* __restrict__ wb3, const float* __restrict__ b3,
    float* __restrict__ dmo) {
  __shared__ unsigned short sLo[8448];
  __shared__ unsigned short sT1[32][520];
  unsigned short (*sA)[136]  = (unsigned short(*)[136])sLo;
  unsigned short (*sT2)[264] = (unsigned short(*)[264])sLo;

  const int tid  = threadIdx.x;
  const int e0   = blockIdx.x * 32;
  const int lane = tid & 63;
  const int wv   = tid >> 6;
  const int r16  = lane & 15;
  const int quad = lane >> 4;

  const int sr = tid >> 3;
  const int t8 = tid & 7;
  const int se = e0 + sr;
  const int vsrc = adj[se];
  const int vdst = adj[E_ + se];

  float4 pf0, pf1, pf2, pf3;
  float4 dm0, dm1, dm2, dm3;
  {
    const float4* sp = (const float4*)(xout + (size_t)vsrc * D_ + t8 * 16);
    pf0 = sp[0]; pf1 = sp[1]; pf2 = sp[2]; pf3 = sp[3];
  }

  const f32x4 zz = {0.f, 0.f, 0.f, 0.f};
  f32x4 acc1[8][2];
#pragma unroll
  for (int i = 0; i < 8; ++i) { acc1[i][0] = zz; acc1[i][1] = zz; }

  for (int c = 0; c < 6; ++c) {
    const int k0 = c * 128;
    __syncthreads();
    {
      unsigned short tmp[16];
      if (c == 2 || c == 3) {
        int jb = (c - 2) * 128 + t8 * 16;
#pragma unroll
        for (int j = 0; j < 16; ++j) {
          const float4* lw = (const float4*)(lin_w + (size_t)(jb + j) * DIN_);
          float4 w0 = lw[0], w1 = lw[1], w2 = lw[2], w3 = lw[3];
          float acc = lin_b[jb + j];
          acc += dm0.x * w0.x + dm0.y * w0.y + dm0.z * w0.z + dm0.w * w0.w;
          acc += dm1.x * w1.x + dm1.y * w1.y + dm1.z * w1.z + dm1.w * w1.w;
          acc += dm2.x * w2.x + dm2.y * w2.y + dm2.z * w2.z + dm2.w * w2.w;
          acc += dm3.x * w3.x + dm3.y * w3.y + dm3.z * w3.z + dm3.w * w3.w;
          tmp[j] = f2b(acc);
        }
      } else {
        tmp[0]  = f2b(pf0.x); tmp[1]  = f2b(pf0.y); tmp[2]  = f2b(pf0.z); tmp[3]  = f2b(pf0.w);
        tmp[4]  = f2b(pf1.x); tmp[5]  = f2b(pf1.y); tmp[6]  = f2b(pf1.z); tmp[7]  = f2b(pf1.w);
        tmp[8]  = f2b(pf2.x); tmp[9]  = f2b(pf2.y); tmp[10] = f2b(pf2.z); tmp[11] = f2b(pf2.w);
        tmp[12] = f2b(pf3.x); tmp[13] = f2b(pf3.y); tmp[14] = f2b(pf3.z); tmp[15] = f2b(pf3.w);
      }
      unsigned short* dstp = &sA[sr][t8 * 16];
      uint4 q0v = {pack2(tmp[0], tmp[1]),   pack2(tmp[2], tmp[3]),
                   pack2(tmp[4], tmp[5]),   pack2(tmp[6], tmp[7])};
      uint4 q1v = {pack2(tmp[8], tmp[9]),   pack2(tmp[10], tmp[11]),
                   pack2(tmp[12], tmp[13]), pack2(tmp[14], tmp[15])};
      *(uint4*)(dstp) = q0v;
      *(uint4*)(dstp + 8) = q1v;
    }
    if (c == 0) {
      const float4* sp = (const float4*)(xout + (size_t)vsrc * D_ + 128 + t8 * 16);
      pf0 = sp[0]; pf1 = sp[1]; pf2 = sp[2]; pf3 = sp[3];
    } else if (c == 1) {
      const float4* dp = (const float4*)(dmap + (size_t)se * DIN_);
      dm0 = ntload4(dp); dm1 = ntload4(dp + 1); dm2 = ntload4(dp + 2); dm3 = ntload4(dp + 3);
    } else if (c == 3) {
      const float4* sp = (const float4*)(xout + (size_t)vdst * D_ + t8 * 16);
      pf0 = sp[0]; pf1 = sp[1]; pf2 = sp[2]; pf3 = sp[3];
    } else if (c == 4) {
      const float4* sp = (const float4*)(xout + (size_t)vdst * D_ + 128 + t8 * 16);
      pf0 = sp[0]; pf1 = sp[1]; pf2 = sp[2]; pf3 = sp[3];
    }
    __syncthreads();
#pragma unroll
    for (int kk = 0; kk < 4; ++kk) {
      bf16_8 a0 = frag16(&sA[r16][kk * 32 + quad * 8]);
      bf16_8 a1 = frag16(&sA[16 + r16][kk * 32 + quad * 8]);
#pragma unroll
      for (int i = 0; i < 8; ++i) {
        const unsigned short* bp =
            wb1 + (size_t)(wv * 128 + i * 16 + r16) * 768 + k0 + kk * 32 + quad * 8;
        bf16_8 bf = frag16(bp);
        acc1[i][0] = __builtin_amdgcn_mfma_f32_16x16x32_bf16(a0, bf, acc1[i][0], 0, 0, 0);
        acc1[i][1] = __builtin_amdgcn_mfma_f32_16x16x32_bf16(a1, bf, acc1[i][1], 0, 0, 0);
      }
    }
  }
#pragma unroll
  for (int i = 0; i < 8; ++i) {
    int col = wv * 128 + i * 16 + r16;
    float bb = b1[col];
#pragma unroll
    for (int m = 0; m < 2; ++m)
#pragma unroll
      for (int r = 0; r < 4; ++r) {
        int row = m * 16 + quad * 4 + r;
        sT1[row][col] = f2b(gelu_exact(acc1[i][m][r] + bb));
      }
  }
  __syncthreads();

  f32x4 acc2[4][2];
#pragma unroll
  for (int i = 0; i < 4; ++i) { acc2[i][0] = zz; acc2[i][1] = zz; }
#pragma unroll 4
  for (int ks = 0; ks < 16; ++ks) {
    bf16_8 a0 = frag16(&sT1[r16][ks * 32 + quad * 8]);
    bf16_8 a1 = frag16(&sT1[16 + r16][ks * 32 + quad * 8]);
#pragma unroll
    for (int i = 0; i < 4; ++i) {
      const unsigned short* bp =
          wb2 + (size_t)(wv * 64 + i * 16 + r16) * 512 + ks * 32 + quad * 8;
      bf16_8 bf = frag16(bp);
      acc2[i][0] = __builtin_amdgcn_mfma_f32_16x16x32_bf16(a0, bf, acc2[i][0], 0, 0, 0);
      acc2[i][1] = __builtin_amdgcn_mfma_f32_16x16x32_bf16(a1, bf, acc2[i][1], 0, 0, 0);
    }
  }
#pragma unroll
  for (int i = 0; i < 4; ++i) {
    int col = wv * 64 + i * 16 + r16;
    float bb = b2[col];
#pragma unroll
    for (int m = 0; m < 2; ++m)
#pragma unroll
      for (int r = 0; r < 4; ++r) {
        int row = m * 16 + quad * 4 + r;
        sT2[row][col] = f2b(gelu_exact(acc2[i][m][r] + bb));
      }
  }
  __syncthreads();

  if (wv < 2) {
    f32x4 acc3 = zz;
#pragma unroll
    for (int ks = 0; ks < 8; ++ks) {
      bf16_8 a = frag16(&sT2[wv * 16 + r16][ks * 32 + quad * 8]);
      bf16_8 b = frag16(wb3 + (size_t)r16 * 256 + ks * 32 + quad * 8);
      acc3 = __builtin_amdgcn_mfma_f32_16x16x32_bf16(a, b, acc3, 0, 0, 0);
    }
    float bb = b3[r16];
#pragma unroll
    for (int r = 0; r < 4; ++r) {
      int row = wv * 16 + quad * 4 + r;
      __builtin_nontemporal_store(acc3[r] + bb, &dmo[(size_t)(e0 + row) * DIN_ + r16]);
    }
  }
}

extern "C" void kernel_launch(void* const* d_in, const int* in_sizes, int n_in,
                              void* d_out, int out_size, void* d_ws, size_t ws_size,
                              hipStream_t stream) {
  const float* input = (const float*)d_in[0];
  const int*   adj   = (const int*)d_in[1];
  const float* h0    = (const float*)d_in[2];
  const void*  lamda = d_in[3];
  const float* alpha = (const float*)d_in[4];
  const void*  lll   = d_in[5];
  const float* dmap  = (const float*)d_in[6];
  const float* nrm   = (const float*)d_in[7];
  const float* Wl    = (const float*)d_in[8];
  const float* Wg    = (const float*)d_in[9];
  const float* lin_w = (const float*)d_in[10];
  const float* lin_b = (const float*)d_in[11];
  const float* w1    = (const float*)d_in[12];
  const float* b1    = (const float*)d_in[13];
  const float* w2    = (const float*)d_in[14];
  const float* b2    = (const float*)d_in[15];
  const float* w3    = (const float*)d_in[16];
  const float* b3    = (const float*)d_in[17];
  const float* ipw   = (const float*)d_in[18];
  const float* ipb   = (const float*)d_in[19];
  const float* opw   = (const float*)d_in[20];
  const float* opb   = (const float*)d_in[21];
  float* out = (float*)d_out;
  float* dmo = out + (size_t)N_ * D_;

  // ---- workspace layout ----
  float* ws   = (float*)d_ws;
  float* xout = ws;                               // N*D f32
  float* qkv  = xout + (size_t)N_ * D_;           // N*3D f32
  float* atto = qkv  + (size_t)N_ * 3 * D_;       // N*D f32
  float* hgl  = atto + (size_t)N_ * D_;           // N*D f32
  unsigned short* wb1 = (unsigned short*)(hgl + (size_t)N_ * D_);  // 512*768
  unsigned short* wb2 = wb1 + 512 * 768;          // 256*512
  unsigned short* wb3 = wb2 + 256 * 512;          // 16*256
  unsigned short* Qb  = wb3 + 16 * 256;           // 2*N*128
  unsigned short* Kb  = Qb + 2 * N_ * HD_;        // 2*N*128
  unsigned short* Vt  = Kb + 2 * N_ * HD_;        // 2*128*N
  unsigned short* t1b = Vt + 2 * HD_ * N_;        // E*512  (fast path only)
  unsigned short* t2b = t1b + (size_t)E_ * 512;   // E*256  (fast path; aliases eab)
  unsigned short* eab = t2b;                      // E*256  (consumed before t2 written)
  const size_t fast_need = (size_t)((char*)(t2b + (size_t)E_ * 256) - (char*)d_ws);
  const bool fast = ws_size >= fast_need;

  // bf16 weight conversion (native [out,in] layout == MFMA B-frag layout)
  k_f2b<<<dim3((512 * 768 + 255) / 256), 256, 0, stream>>>(w1, wb1, 512 * 768);
  k_f2b<<<dim3((256 * 512 + 255) / 256), 256, 0, stream>>>(w2, wb2, 256 * 512);
  k_f2b<<<dim3((16 * 256 + 255) / 256), 256, 0, stream>>>(w3, wb3, 16 * 256);

  // x_out = input, then scatter-add messages
  k_copy4<<<dim3(N_ * D_ / 4 / 256), 256, 0, stream>>>((const float4*)input, (float4*)xout,
                                                       N_ * D_ / 4);
  if (fast) {
    k_edge_attr<<<dim3(E_ / 16), 256, 0, stream>>>(dmap, lin_w, lin_b, eab);
    k_scatter_ea<<<dim3(E_ / 4), 256, 0, stream>>>(input, adj, eab, nrm, xout);
  } else {
    k_scatter<<<dim3(E_ / 4), 256, 0, stream>>>(input, adj, dmap, nrm, lin_w, lin_b, xout);
  }

  // MHA: qkv proj -> bf16 split/transpose -> MFMA flash attention -> out_proj
  k_gemm_bt<<<dim3(D3_ / 64, N_ / 64), 256, 0, stream>>>(input, ipw, ipb, qkv, N_, D3_, D_);
  k_qk2b<<<dim3(N_ * 512 / 8 / 256), 256, 0, stream>>>(qkv, Qb, Kb);
  k_v2t<<<dim3(N_ / 64, 2), 256, 0, stream>>>(qkv, Vt);
  k_attn_mfma<<<dim3(N_ / 16, 2), 256, 0, stream>>>(Qb, Kb, Vt, atto);
  k_gemm_bt<<<dim3(D_ / 64, N_ / 64), 256, 0, stream>>>(atto, opw, opb, hgl, N_, D_, D_);

  // output[N,D]
  k_final<<<dim3(4, N_ / 64), 256, 0, stream>>>(xout, hgl, h0, Wl, Wg, alpha, lamda, lll, out);

  // dm_out[E,16]
  if (fast) {
    k_mlp_gemm1<<<dim3(E_ / 128, 4), 256, 0, stream>>>(xout, adj, eab, wb1, b1, t1b);
    k_mlp_gemm2<<<dim3(E_ / 128, 2), 256, 0, stream>>>(t1b, wb2, b2, t2b);
    k_mlp_gemm3<<<dim3(E_ / 64), 256, 0, stream>>>(t2b, wb3, b3, dmo);
  } else {
    k_edge_mlp_mfma<<<dim3(E_ / 32), 256, 0, stream>>>(xout, adj, dmap, lin_w, lin_b,
                                                       wb1, b1, wb2, b2, wb3, b3, dmo);
  }
}

// Round 6
// 1122.197 us; speedup vs baseline: 3.6982x; 1.3341x over previous
//
#include <hip/hip_runtime.h>
#include <hip/hip_bf16.h>
#include <math.h>

// Problem constants
constexpr int N_   = 4096;
constexpr int E_   = 131072;
constexpr int D_   = 256;
constexpr int DIN_ = 16;
constexpr int D3_  = 768;   // 3*D
constexpr int HD_  = 128;   // head dim

typedef __bf16 bf16_8 __attribute__((ext_vector_type(8)));
typedef float  f32x4  __attribute__((ext_vector_type(4)));
typedef float  f32x4v __attribute__((ext_vector_type(4)));

// ---- bf16 helpers ----
__device__ __forceinline__ unsigned short f2b(float f) {
  unsigned int u = __float_as_uint(f);
  u = u + 0x7fffu + ((u >> 16) & 1u);   // round-to-nearest-even
  return (unsigned short)(u >> 16);
}
__device__ __forceinline__ float b2f(unsigned short s) {
  return __uint_as_float(((unsigned int)s) << 16);
}
__device__ __forceinline__ unsigned int pack2(unsigned short lo, unsigned short hi) {
  return (unsigned int)lo | ((unsigned int)hi << 16);
}
__device__ __forceinline__ bf16_8 frag16(const unsigned short* p) {
  uint4 v = *(const uint4*)p;           // 16B load (LDS b128 or global dwordx4)
  return __builtin_bit_cast(bf16_8, v);
}
__device__ __forceinline__ float4 ntload4(const void* p) {
  f32x4v v = __builtin_nontemporal_load((const f32x4v*)p);
  float4 r;
  r.x = v[0]; r.y = v[1]; r.z = v[2]; r.w = v[3];
  return r;
}

// Python scalar may arrive as int32 or float32 bits; values here are small ints.
__device__ __forceinline__ float scalar_as_float(const void* p) {
  int iv = *(const int*)p;
  if (iv >= 1 && iv <= 1000000) return (float)iv;  // plausible int
  return __int_as_float(iv);                       // else float bits
}

__device__ __forceinline__ float gelu_exact(float v) {
  return 0.5f * v * (1.0f + erff(v * 0.70710678118654752f));
}

// ---------------- f32 -> bf16 convert ----------------
__global__ void k_f2b(const float* __restrict__ src, unsigned short* __restrict__ dst, int n) {
  int i = blockIdx.x * 256 + threadIdx.x;
  if (i < n) dst[i] = f2b(src[i]);
}

// ---------------- copy (float4) ----------------
__global__ void k_copy4(const float4* __restrict__ src, float4* __restrict__ dst, int n4) {
  int idx = blockIdx.x * 256 + threadIdx.x;
  if (idx < n4) dst[idx] = src[idx];
}

// ---------------- edge_attr precompute: eab16[E,256] = bf16(dmap@lin_w^T+lin_b) ----------------
__global__ __launch_bounds__(256) void k_edge_attr(
    const float* __restrict__ dmap, const float* __restrict__ lin_w,
    const float* __restrict__ lin_b, unsigned short* __restrict__ eab) {
  __shared__ float sdm[16][17];
  int tid = threadIdx.x;
  int e0 = blockIdx.x * 16;
  int el = tid >> 4, jg = tid & 15;
  sdm[el][jg] = dmap[(size_t)(e0 + el) * DIN_ + jg];
  __syncthreads();
  float dm[DIN_];
#pragma unroll
  for (int k = 0; k < DIN_; ++k) dm[k] = sdm[el][k];
  unsigned int pk[8];
#pragma unroll
  for (int j2 = 0; j2 < 8; ++j2) {
    unsigned short o2[2];
#pragma unroll
    for (int s = 0; s < 2; ++s) {
      int col = jg * 16 + j2 * 2 + s;
      const float4* lw = (const float4*)(lin_w + (size_t)col * DIN_);
      float4 w0 = lw[0], w1 = lw[1], w2 = lw[2], w3 = lw[3];
      float acc = lin_b[col];
      acc += dm[0] * w0.x + dm[1] * w0.y + dm[2] * w0.z + dm[3] * w0.w;
      acc += dm[4] * w1.x + dm[5] * w1.y + dm[6] * w1.z + dm[7] * w1.w;
      acc += dm[8] * w2.x + dm[9] * w2.y + dm[10] * w2.z + dm[11] * w2.w;
      acc += dm[12] * w3.x + dm[13] * w3.y + dm[14] * w3.z + dm[15] * w3.w;
      o2[s] = f2b(acc);
    }
    pk[j2] = pack2(o2[0], o2[1]);
  }
  uint4* dst = (uint4*)(eab + (size_t)(e0 + el) * D_ + jg * 16);
  dst[0] = make_uint4(pk[0], pk[1], pk[2], pk[3]);
  dst[1] = make_uint4(pk[4], pk[5], pk[6], pk[7]);
}

// ================= CSR build (per-launch) + gather aggregation =================
__global__ void k_zero(int* __restrict__ p, int n) {
  int i = blockIdx.x * 256 + threadIdx.x;
  if (i < n) p[i] = 0;
}
__global__ void k_hist(const int* __restrict__ adj, int* __restrict__ cnt) {
  int e = blockIdx.x * 256 + threadIdx.x;
  atomicAdd(&cnt[adj[E_ + e]], 1);
}
// exclusive scan of cnt[4096] -> off[0..4096], cur = off
__global__ __launch_bounds__(1024) void k_scan(const int* __restrict__ cnt,
                                               int* __restrict__ off, int* __restrict__ cur) {
  __shared__ int ps[1024];
  int tid = threadIdx.x;
  int base = tid * 4;
  int a0 = cnt[base], a1 = cnt[base + 1], a2 = cnt[base + 2], a3 = cnt[base + 3];
  int tsum = a0 + a1 + a2 + a3;
  ps[tid] = tsum;
  __syncthreads();
  for (int st = 1; st < 1024; st <<= 1) {
    int v = (tid >= st) ? ps[tid - st] : 0;
    __syncthreads();
    ps[tid] += v;
    __syncthreads();
  }
  int excl = ps[tid] - tsum;
  int o0 = excl, o1 = excl + a0, o2 = o1 + a1, o3 = o2 + a2;
  off[base] = o0; off[base + 1] = o1; off[base + 2] = o2; off[base + 3] = o3;
  cur[base] = o0; cur[base + 1] = o1; cur[base + 2] = o2; cur[base + 3] = o3;
  if (tid == 1023) off[4096] = o3 + a3;
}
__global__ void k_bucket(const int* __restrict__ adj, int* __restrict__ cur,
                         int* __restrict__ perm) {
  int e = blockIdx.x * 256 + threadIdx.x;
  int p = atomicAdd(&cur[adj[E_ + e]], 1);
  perm[p] = e;
}
// xout[n][d] = input[n][d] + sum_{e in in(n)} nrm[e]*(input[src[e]][d] + ea[e][d])
__global__ __launch_bounds__(256) void k_gather(
    const float* __restrict__ x, const int* __restrict__ adj,
    const unsigned short* __restrict__ eab, const float* __restrict__ nrm,
    const int* __restrict__ off, const int* __restrict__ perm,
    float* __restrict__ xout) {
  int n = blockIdx.x, t = threadIdx.x;
  int beg = off[n], end = off[n + 1];
  float acc = x[(size_t)n * D_ + t];
  int i = beg;
  for (; i + 1 < end; i += 2) {
    int e0 = perm[i], e1 = perm[i + 1];
    int s0 = adj[e0], s1 = adj[e1];
    float w0 = nrm[e0], w1 = nrm[e1];
    float xa = x[(size_t)s0 * D_ + t];
    float xb = x[(size_t)s1 * D_ + t];
    float ea0 = b2f(eab[(size_t)e0 * D_ + t]);
    float ea1 = b2f(eab[(size_t)e1 * D_ + t]);
    acc += w0 * (xa + ea0) + w1 * (xb + ea1);
  }
  if (i < end) {
    int e0 = perm[i];
    int s0 = adj[e0];
    float w0 = nrm[e0];
    acc += w0 * (x[(size_t)s0 * D_ + t] + b2f(eab[(size_t)e0 * D_ + t]));
  }
  xout[(size_t)n * D_ + t] = acc;
}

// ---------------- legacy scatter (fallback path) ----------------
__global__ __launch_bounds__(256) void k_scatter(
    const float* __restrict__ x, const int* __restrict__ adj,
    const float* __restrict__ dmap, const float* __restrict__ nrm,
    const float* __restrict__ lin_w, const float* __restrict__ lin_b,
    float* __restrict__ xout) {
  __shared__ float s_dm[4][DIN_];
  int te = threadIdx.x >> 6;
  int d4 = threadIdx.x & 63;
  int e  = blockIdx.x * 4 + te;
  if (d4 < DIN_) s_dm[te][d4] = dmap[(size_t)e * DIN_ + d4];
  __syncthreads();
  int vs = adj[e];
  int vd = adj[E_ + e];
  float w = nrm[e];
  int d = d4 * 4;
  float4 xs = *(const float4*)(x + (size_t)vs * D_ + d);
  float ea[4];
#pragma unroll
  for (int q = 0; q < 4; q++) {
    const float* lw = lin_w + (size_t)(d + q) * DIN_;
    float acc = lin_b[d + q];
#pragma unroll
    for (int k = 0; k < DIN_; k++) acc += s_dm[te][k] * lw[k];
    ea[q] = acc;
  }
  float* op = xout + (size_t)vd * D_ + d;
  atomicAdd(op + 0, w * (xs.x + ea[0]));
  atomicAdd(op + 1, w * (xs.y + ea[1]));
  atomicAdd(op + 2, w * (xs.z + ea[2]));
  atomicAdd(op + 3, w * (xs.w + ea[3]));
}

// ---------------- C[M,N] = A[M,K] @ B[N,K]^T + bias ----------------
__global__ __launch_bounds__(256) void k_gemm_bt(
    const float* __restrict__ A, const float* __restrict__ B,
    const float* __restrict__ bias, float* __restrict__ C,
    int M, int Nn, int K) {
  __shared__ float sA[16][68];
  __shared__ float sB[16][68];
  int bm = blockIdx.y * 64, bn = blockIdx.x * 64;
  int tid = threadIdx.x;
  int tr = tid >> 4, tc = tid & 15;
  float acc[4][4] = {};
  for (int k0 = 0; k0 < K; k0 += 16) {
    for (int i = tid; i < 1024; i += 256) {
      int r = i >> 4, c = i & 15;
      sA[c][r] = A[(size_t)(bm + r) * K + k0 + c];
      sB[c][r] = B[(size_t)(bn + r) * K + k0 + c];
    }
    __syncthreads();
#pragma unroll
    for (int kk = 0; kk < 16; kk++) {
      float av[4], bv[4];
#pragma unroll
      for (int i = 0; i < 4; i++) av[i] = sA[kk][tr * 4 + i];
#pragma unroll
      for (int j = 0; j < 4; j++) bv[j] = sB[kk][tc * 4 + j];
#pragma unroll
      for (int i = 0; i < 4; i++)
#pragma unroll
        for (int j = 0; j < 4; j++) acc[i][j] += av[i] * bv[j];
    }
    __syncthreads();
  }
#pragma unroll
  for (int i = 0; i < 4; i++) {
    int r = bm + tr * 4 + i;
#pragma unroll
    for (int j = 0; j < 4; j++) {
      int c = bn + tc * 4 + j;
      C[(size_t)r * Nn + c] = acc[i][j] + bias[c];
    }
  }
}

// ---------------- qkv split: fp32 [N,768] -> bf16 Qb/Kb [h][n][128] ----------------
__global__ void k_qk2b(const float* __restrict__ qkv,
                       unsigned short* __restrict__ Qb, unsigned short* __restrict__ Kb) {
  int off = (blockIdx.x * 256 + threadIdx.x) * 8;   // over N*512
  int n = off >> 9, c = off & 511;
  const float* src = qkv + (size_t)n * D3_ + c;     // Q cols 0..255, K cols 256..511
  float4 a = *(const float4*)src;
  float4 b = *(const float4*)(src + 4);
  uint4 p = {pack2(f2b(a.x), f2b(a.y)), pack2(f2b(a.z), f2b(a.w)),
             pack2(f2b(b.x), f2b(b.y)), pack2(f2b(b.z), f2b(b.w))};
  int cc = c & 255;
  int hh = cc >> 7, d = cc & 127;
  unsigned short* dst = (c < 256 ? Qb : Kb) + (size_t)hh * N_ * HD_ + (size_t)n * HD_ + d;
  *(uint4*)dst = p;
}

// ---------------- V transpose: fp32 qkv V-cols -> bf16 Vt [h][128][N] ----------------
__global__ __launch_bounds__(256) void k_v2t(const float* __restrict__ qkv,
                                             unsigned short* __restrict__ Vt) {
  __shared__ unsigned short sv[64][136];
  int h = blockIdx.y;
  int n0 = blockIdx.x * 64;
  int tid = threadIdx.x;
#pragma unroll
  for (int it = 0; it < 4; ++it) {
    int off = (tid + it * 256) * 8;
    int r = off >> 7, d = off & 127;
    const float* src = qkv + (size_t)(n0 + r) * D3_ + 2 * D_ + h * HD_ + d;
    float4 a = *(const float4*)src;
    float4 b = *(const float4*)(src + 4);
    uint4 p = {pack2(f2b(a.x), f2b(a.y)), pack2(f2b(a.z), f2b(a.w)),
               pack2(f2b(b.x), f2b(b.y)), pack2(f2b(b.z), f2b(b.w))};
    *(uint4*)&sv[r][d] = p;
  }
  __syncthreads();
#pragma unroll
  for (int it = 0; it < 4; ++it) {
    int off = (tid + it * 256) * 8;
    int d = off >> 6, k = off & 63;
    unsigned short t[8];
#pragma unroll
    for (int j = 0; j < 8; ++j) t[j] = sv[k + j][d];
    uint4 p = {pack2(t[0], t[1]), pack2(t[2], t[3]),
               pack2(t[4], t[5]), pack2(t[6], t[7])};
    *(uint4*)(Vt + (size_t)h * HD_ * N_ + (size_t)d * N_ + n0 + k) = p;
  }
}

// ---------------- MFMA flash attention, H=2, HD=128 ----------------
__global__ __launch_bounds__(256) void k_attn_mfma(
    const unsigned short* __restrict__ Qb, const unsigned short* __restrict__ Kb,
    const unsigned short* __restrict__ Vt, float* __restrict__ o_out) {
  __shared__ unsigned short sK[64][136];   // keys x dims (+8 pad)
  __shared__ unsigned short sV[128][72];   // dims x keys (+8 pad)
  __shared__ float          sS[16][68];    // scores
  __shared__ unsigned short sP[16][72];    // probs bf16 (A-frag layout)
  __shared__ float sm[16], sl[16], sa[16];

  const int tid  = threadIdx.x;
  const int h    = blockIdx.y;
  const int q0   = blockIdx.x * 16;
  const int lane = tid & 63;
  const int wv   = tid >> 6;
  const int r16  = lane & 15;
  const int quad = lane >> 4;

  bf16_8 qf[4];
#pragma unroll
  for (int kk = 0; kk < 4; ++kk)
    qf[kk] = frag16(Qb + (size_t)h * N_ * HD_ + (size_t)(q0 + r16) * HD_ + kk * 32 + quad * 8);

  if (tid < 16) { sm[tid] = -1e30f; sl[tid] = 0.f; }

  const f32x4 zz = {0.f, 0.f, 0.f, 0.f};
  f32x4 o0 = zz, o1 = zz;

  const unsigned short* Kh = Kb + (size_t)h * N_ * HD_;
  const unsigned short* Vh = Vt + (size_t)h * HD_ * N_;

  for (int c0 = 0; c0 < N_; c0 += 64) {
    __syncthreads();
#pragma unroll
    for (int it = 0; it < 4; ++it) {
      int off = (tid + it * 256) * 8;
      int key = off >> 7, d = off & 127;
      *(uint4*)&sK[key][d] = *(const uint4*)(Kh + (size_t)(c0 + key) * HD_ + d);
    }
#pragma unroll
    for (int it = 0; it < 4; ++it) {
      int off = (tid + it * 256) * 8;
      int d = off >> 6, k = off & 63;
      *(uint4*)&sV[d][k] = *(const uint4*)(Vh + (size_t)d * N_ + c0 + k);
    }
    __syncthreads();
    f32x4 s = zz;
#pragma unroll
    for (int kk = 0; kk < 4; ++kk) {
      bf16_8 bf = frag16(&sK[wv * 16 + r16][kk * 32 + quad * 8]);
      s = __builtin_amdgcn_mfma_f32_16x16x32_bf16(qf[kk], bf, s, 0, 0, 0);
    }
    const float sc = 0.08838834764831845f;   // 1/sqrt(128)
#pragma unroll
    for (int r = 0; r < 4; ++r)
      sS[quad * 4 + r][wv * 16 + r16] = s[r] * sc;
    __syncthreads();
    {
      int row = tid >> 4, i = tid & 15;
      float4 v = *(const float4*)&sS[row][i * 4];
      float mx = fmaxf(fmaxf(v.x, v.y), fmaxf(v.z, v.w));
#pragma unroll
      for (int m = 1; m <= 8; m <<= 1) mx = fmaxf(mx, __shfl_xor(mx, m));
      float mo = sm[row];
      float mn = fmaxf(mo, mx);
      float p0 = __expf(v.x - mn), p1 = __expf(v.y - mn);
      float p2 = __expf(v.z - mn), p3 = __expf(v.w - mn);
      float ps = p0 + p1 + p2 + p3;
#pragma unroll
      for (int m = 1; m <= 8; m <<= 1) ps += __shfl_xor(ps, m);
      uint2 pk = {pack2(f2b(p0), f2b(p1)), pack2(f2b(p2), f2b(p3))};
      *(uint2*)&sP[row][i * 4] = pk;
      if (i == 0) {
        float al = __expf(mo - mn);
        sl[row] = sl[row] * al + ps;
        sm[row] = mn;
        sa[row] = al;
      }
    }
    __syncthreads();
    {
      float al0 = sa[quad * 4 + 0], al1 = sa[quad * 4 + 1];
      float al2 = sa[quad * 4 + 2], al3 = sa[quad * 4 + 3];
      o0[0] *= al0; o0[1] *= al1; o0[2] *= al2; o0[3] *= al3;
      o1[0] *= al0; o1[1] *= al1; o1[2] *= al2; o1[3] *= al3;
#pragma unroll
      for (int kk = 0; kk < 2; ++kk) {
        bf16_8 pa = frag16(&sP[r16][kk * 32 + quad * 8]);
        bf16_8 v0 = frag16(&sV[wv * 32 + r16][kk * 32 + quad * 8]);
        bf16_8 v1 = frag16(&sV[wv * 32 + 16 + r16][kk * 32 + quad * 8]);
        o0 = __builtin_amdgcn_mfma_f32_16x16x32_bf16(pa, v0, o0, 0, 0, 0);
        o1 = __builtin_amdgcn_mfma_f32_16x16x32_bf16(pa, v1, o1, 0, 0, 0);
      }
    }
  }
  {
    float i0 = 1.f / sl[quad * 4 + 0], i1 = 1.f / sl[quad * 4 + 1];
    float i2 = 1.f / sl[quad * 4 + 2], i3 = 1.f / sl[quad * 4 + 3];
    float* base = o_out + (size_t)q0 * D_ + h * HD_ + wv * 32 + r16;
    base[(size_t)(quad * 4 + 0) * D_] = o0[0] * i0;
    base[(size_t)(quad * 4 + 1) * D_] = o0[1] * i1;
    base[(size_t)(quad * 4 + 2) * D_] = o0[2] * i2;
    base[(size_t)(quad * 4 + 3) * D_] = o0[3] * i3;
    float* base1 = base + 16;
    base1[(size_t)(quad * 4 + 0) * D_] = o1[0] * i0;
    base1[(size_t)(quad * 4 + 1) * D_] = o1[1] * i1;
    base1[(size_t)(quad * 4 + 2) * D_] = o1[2] * i2;
    base1[(size_t)(quad * 4 + 3) * D_] = o1[3] * i3;
  }
}

// ---------------- final combine ----------------
__global__ __launch_bounds__(256) void k_final(
    const float* __restrict__ hl, const float* __restrict__ hg, const float* __restrict__ h0,
    const float* __restrict__ Wl, const float* __restrict__ Wg,
    const float* __restrict__ alpha_p, const void* lamda_p, const void* l_p,
    float* __restrict__ out) {
  __shared__ float sA[16][68];
  __shared__ float sB[16][68];
  float theta = fminf(1.f, logf(scalar_as_float(lamda_p) / scalar_as_float(l_p) + 1.f));
  float a = alpha_p[0];
  int bm = blockIdx.y * 64, bn = blockIdx.x * 64;
  int tid = threadIdx.x, tr = tid >> 4, tc = tid & 15;
  float acc[4][4] = {};
  for (int k0 = 0; k0 < 1024; k0 += 16) {
    for (int i = tid; i < 1024; i += 256) {
      int r = i >> 4, c = i & 15;
      int k = k0 + c;
      const float* src = (k < 256) ? hl : (k < 512) ? h0 : (k < 768) ? hg : h0;
      sA[c][r] = src[(size_t)(bm + r) * 256 + (k & 255)];
    }
    for (int i = tid; i < 1024; i += 256) {
      int kk = i >> 6, j = i & 63;
      int k = k0 + kk;
      const float* Bp = (k < 512) ? (Wl + (size_t)k * 256) : (Wg + (size_t)(k - 512) * 256);
      sB[kk][j] = Bp[bn + j];
    }
    __syncthreads();
#pragma unroll
    for (int kk = 0; kk < 16; kk++) {
      float av[4], bv[4];
#pragma unroll
      for (int i = 0; i < 4; i++) av[i] = sA[kk][tr * 4 + i];
#pragma unroll
      for (int j = 0; j < 4; j++) bv[j] = sB[kk][tc * 4 + j];
#pragma unroll
      for (int i = 0; i < 4; i++)
#pragma unroll
        for (int j = 0; j < 4; j++) acc[i][j] += av[i] * bv[j];
    }
    __syncthreads();
  }
  float omt = 1.f - theta;
#pragma unroll
  for (int i = 0; i < 4; i++) {
    int r = bm + tr * 4 + i;
#pragma unroll
    for (int j = 0; j < 4; j++) {
      int c = bn + tc * 4 + j;
      size_t idx = (size_t)r * 256 + c;
      out[idx] = theta * acc[i][j] + omt * ((1.f - a) * (hl[idx] + hg[idx]) + 2.f * a * h0[idx]);
    }
  }
}

// ================= edge MLP as tiled GEMMs (fast path) =================
__global__ __launch_bounds__(256) void k_mlp_gemm1(
    const float* __restrict__ xout, const int* __restrict__ adj,
    const unsigned short* __restrict__ eab, const unsigned short* __restrict__ wb1,
    const float* __restrict__ b1, unsigned short* __restrict__ t1) {
  __shared__ unsigned short sA[128][72];   // 18432 B
  __shared__ unsigned short sB[128][72];   // 18432 B
  const int tid  = threadIdx.x;
  const int e0   = blockIdx.x * 128;
  const int j0   = blockIdx.y * 128;
  const int lane = tid & 63, wv = tid >> 6;
  const int r16  = lane & 15, quad = lane >> 4;
  const int sr   = tid >> 1;            // staged row 0..127
  const int sh   = (tid & 1) * 32;      // col half (elems)
  const int vsrc = adj[e0 + sr];
  const int vdst = adj[E_ + e0 + sr];

  const f32x4 zz = {0.f, 0.f, 0.f, 0.f};
  f32x4 acc[2][8];
#pragma unroll
  for (int m = 0; m < 2; ++m)
#pragma unroll
    for (int n = 0; n < 8; ++n) acc[m][n] = zz;

  for (int ki = 0; ki < 12; ++ki) {
    const int k0 = ki * 64;
    __syncthreads();
    {
      const int gc = k0 + sh;
      uint4* dst = (uint4*)&sA[sr][sh];
      if (gc < 256 || gc >= 512) {
        const int node = (gc < 256) ? vsrc : vdst;
        const float4* src = (const float4*)(xout + (size_t)node * D_ + (gc & 255));
        unsigned int pk[16];
#pragma unroll
        for (int q = 0; q < 8; ++q) {
          float4 v = src[q];
          pk[2 * q]     = pack2(f2b(v.x), f2b(v.y));
          pk[2 * q + 1] = pack2(f2b(v.z), f2b(v.w));
        }
#pragma unroll
        for (int i = 0; i < 4; ++i)
          dst[i] = make_uint4(pk[4 * i], pk[4 * i + 1], pk[4 * i + 2], pk[4 * i + 3]);
      } else {
        const uint4* src = (const uint4*)(eab + (size_t)(e0 + sr) * D_ + (gc - 256));
#pragma unroll
        for (int i = 0; i < 4; ++i) dst[i] = src[i];
      }
    }
    {
      const uint4* src = (const uint4*)(wb1 + (size_t)(j0 + sr) * 768 + k0 + sh);
      uint4* dst = (uint4*)&sB[sr][sh];
#pragma unroll
      for (int i = 0; i < 4; ++i) dst[i] = src[i];
    }
    __syncthreads();
#pragma unroll
    for (int kk = 0; kk < 2; ++kk) {
      bf16_8 a0 = frag16(&sA[wv * 32 + r16][kk * 32 + quad * 8]);
      bf16_8 a1 = frag16(&sA[wv * 32 + 16 + r16][kk * 32 + quad * 8]);
#pragma unroll
      for (int n = 0; n < 8; ++n) {
        bf16_8 bf = frag16(&sB[n * 16 + r16][kk * 32 + quad * 8]);
        acc[0][n] = __builtin_amdgcn_mfma_f32_16x16x32_bf16(a0, bf, acc[0][n], 0, 0, 0);
        acc[1][n] = __builtin_amdgcn_mfma_f32_16x16x32_bf16(a1, bf, acc[1][n], 0, 0, 0);
      }
    }
  }
  float bias[8];
#pragma unroll
  for (int n = 0; n < 8; ++n) bias[n] = b1[j0 + n * 16 + r16];
#pragma unroll
  for (int m = 0; m < 2; ++m)
#pragma unroll
    for (int n = 0; n < 8; ++n)
#pragma unroll
      for (int rg = 0; rg < 4; ++rg) {
        int row = e0 + wv * 32 + m * 16 + quad * 4 + rg;
        int col = j0 + n * 16 + r16;
        t1[(size_t)row * 512 + col] = f2b(gelu_exact(acc[m][n][rg] + bias[n]));
      }
}

__global__ __launch_bounds__(256) void k_mlp_gemm2(
    const unsigned short* __restrict__ t1, const unsigned short* __restrict__ wb2,
    const float* __restrict__ b2, unsigned short* __restrict__ t2) {
  __shared__ unsigned short sA[128][72];
  __shared__ unsigned short sB[128][72];
  const int tid  = threadIdx.x;
  const int e0   = blockIdx.x * 128;
  const int j0   = blockIdx.y * 128;
  const int lane = tid & 63, wv = tid >> 6;
  const int r16  = lane & 15, quad = lane >> 4;
  const int sr   = tid >> 1;
  const int sh   = (tid & 1) * 32;

  const f32x4 zz = {0.f, 0.f, 0.f, 0.f};
  f32x4 acc[2][8];
#pragma unroll
  for (int m = 0; m < 2; ++m)
#pragma unroll
    for (int n = 0; n < 8; ++n) acc[m][n] = zz;

  for (int ki = 0; ki < 8; ++ki) {
    const int k0 = ki * 64;
    __syncthreads();
    {
      const uint4* src = (const uint4*)(t1 + (size_t)(e0 + sr) * 512 + k0 + sh);
      uint4* dst = (uint4*)&sA[sr][sh];
#pragma unroll
      for (int i = 0; i < 4; ++i) dst[i] = src[i];
    }
    {
      const uint4* src = (const uint4*)(wb2 + (size_t)(j0 + sr) * 512 + k0 + sh);
      uint4* dst = (uint4*)&sB[sr][sh];
#pragma unroll
      for (int i = 0; i < 4; ++i) dst[i] = src[i];
    }
    __syncthreads();
#pragma unroll
    for (int kk = 0; kk < 2; ++kk) {
      bf16_8 a0 = frag16(&sA[wv * 32 + r16][kk * 32 + quad * 8]);
      bf16_8 a1 = frag16(&sA[wv * 32 + 16 + r16][kk * 32 + quad * 8]);
#pragma unroll
      for (int n = 0; n < 8; ++n) {
        bf16_8 bf = frag16(&sB[n * 16 + r16][kk * 32 + quad * 8]);
        acc[0][n] = __builtin_amdgcn_mfma_f32_16x16x32_bf16(a0, bf, acc[0][n], 0, 0, 0);
        acc[1][n] = __builtin_amdgcn_mfma_f32_16x16x32_bf16(a1, bf, acc[1][n], 0, 0, 0);
      }
    }
  }
  float bias[8];
#pragma unroll
  for (int n = 0; n < 8; ++n) bias[n] = b2[j0 + n * 16 + r16];
#pragma unroll
  for (int m = 0; m < 2; ++m)
#pragma unroll
    for (int n = 0; n < 8; ++n)
#pragma unroll
      for (int rg = 0; rg < 4; ++rg) {
        int row = e0 + wv * 32 + m * 16 + quad * 4 + rg;
        int col = j0 + n * 16 + r16;
        t2[(size_t)row * 256 + col] = f2b(gelu_exact(acc[m][n][rg] + bias[n]));
      }
}

__global__ __launch_bounds__(256) void k_mlp_gemm3(
    const unsigned short* __restrict__ t2, const unsigned short* __restrict__ wb3,
    const float* __restrict__ b3, float* __restrict__ dmo) {
  const int tid  = threadIdx.x;
  const int lane = tid & 63, wv = tid >> 6;
  const int r16  = lane & 15, quad = lane >> 4;
  const int eb   = blockIdx.x * 64 + wv * 16;
  const f32x4 zz = {0.f, 0.f, 0.f, 0.f};
  f32x4 acc = zz;
#pragma unroll
  for (int ks = 0; ks < 8; ++ks) {
    bf16_8 a = frag16(t2 + (size_t)(eb + r16) * 256 + ks * 32 + quad * 8);
    bf16_8 b = frag16(wb3 + (size_t)r16 * 256 + ks * 32 + quad * 8);
    acc = __builtin_amdgcn_mfma_f32_16x16x32_bf16(a, b, acc, 0, 0, 0);
  }
  float bb = b3[r16];
#pragma unroll
  for (int rg = 0; rg < 4; ++rg)
    dmo[(size_t)(eb + quad * 4 + rg) * DIN_ + r16] = acc[rg] + bb;
}

// ---------------- fused edge MLP (fallback path) ----------------
__global__ __launch_bounds__(256, 3) void k_edge_mlp_mfma(
    const float* __restrict__ xout, const int* __restrict__ adj,
    const float* __restrict__ dmap,
    const float* __restrict__ lin_w, const float* __restrict__ lin_b,
    const unsigned short* __restrict__ wb1, const float* __restrict__ b1,
    const unsigned short* __restrict__ wb2, const float* __restrict__ b2,
    const unsigned short* __restrict__ wb3, const float* __restrict__ b3,
    float* __restrict__ dmo) {
  __shared__ unsigned short sLo[8448];
  __shared__ unsigned short sT1[32][520];
  unsigned short (*sA)[136]  = (unsigned short(*)[136])sLo;
  unsigned short (*sT2)[264] = (unsigned short(*)[264])sLo;

  const int tid  = threadIdx.x;
  const int e0   = blockIdx.x * 32;
  const int lane = tid & 63;
  const int wv   = tid >> 6;
  const int r16  = lane & 15;
  const int quad = lane >> 4;

  const int sr = tid >> 3;
  const int t8 = tid & 7;
  const int se = e0 + sr;
  const int vsrc = adj[se];
  const int vdst = adj[E_ + se];

  float4 pf0, pf1, pf2, pf3;
  float4 dm0, dm1, dm2, dm3;
  {
    const float4* sp = (const float4*)(xout + (size_t)vsrc * D_ + t8 * 16);
    pf0 = sp[0]; pf1 = sp[1]; pf2 = sp[2]; pf3 = sp[3];
  }

  const f32x4 zz = {0.f, 0.f, 0.f, 0.f};
  f32x4 acc1[8][2];
#pragma unroll
  for (int i = 0; i < 8; ++i) { acc1[i][0] = zz; acc1[i][1] = zz; }

  for (int c = 0; c < 6; ++c) {
    const int k0 = c * 128;
    __syncthreads();
    {
      unsigned short tmp[16];
      if (c == 2 || c == 3) {
        int jb = (c - 2) * 128 + t8 * 16;
#pragma unroll
        for (int j = 0; j < 16; ++j) {
          const float4* lw = (const float4*)(lin_w + (size_t)(jb + j) * DIN_);
          float4 w0 = lw[0], w1 = lw[1], w2 = lw[2], w3 = lw[3];
          float acc = lin_b[jb + j];
          acc += dm0.x * w0.x + dm0.y * w0.y + dm0.z * w0.z + dm0.w * w0.w;
          acc += dm1.x * w1.x + dm1.y * w1.y + dm1.z * w1.z + dm1.w * w1.w;
          acc += dm2.x * w2.x + dm2.y * w2.y + dm2.z * w2.z + dm2.w * w2.w;
          acc += dm3.x * w3.x + dm3.y * w3.y + dm3.z * w3.z + dm3.w * w3.w;
          tmp[j] = f2b(acc);
        }
      } else {
        tmp[0]  = f2b(pf0.x); tmp[1]  = f2b(pf0.y); tmp[2]  = f2b(pf0.z); tmp[3]  = f2b(pf0.w);
        tmp[4]  = f2b(pf1.x); tmp[5]  = f2b(pf1.y); tmp[6]  = f2b(pf1.z); tmp[7]  = f2b(pf1.w);
        tmp[8]  = f2b(pf2.x); tmp[9]  = f2b(pf2.y); tmp[10] = f2b(pf2.z); tmp[11] = f2b(pf2.w);
        tmp[12] = f2b(pf3.x); tmp[13] = f2b(pf3.y); tmp[14] = f2b(pf3.z); tmp[15] = f2b(pf3.w);
      }
      unsigned short* dstp = &sA[sr][t8 * 16];
      uint4 q0v = {pack2(tmp[0], tmp[1]),   pack2(tmp[2], tmp[3]),
                   pack2(tmp[4], tmp[5]),   pack2(tmp[6], tmp[7])};
      uint4 q1v = {pack2(tmp[8], tmp[9]),   pack2(tmp[10], tmp[11]),
                   pack2(tmp[12], tmp[13]), pack2(tmp[14], tmp[15])};
      *(uint4*)(dstp) = q0v;
      *(uint4*)(dstp + 8) = q1v;
    }
    if (c == 0) {
      const float4* sp = (const float4*)(xout + (size_t)vsrc * D_ + 128 + t8 * 16);
      pf0 = sp[0]; pf1 = sp[1]; pf2 = sp[2]; pf3 = sp[3];
    } else if (c == 1) {
      const float4* dp = (const float4*)(dmap + (size_t)se * DIN_);
      dm0 = ntload4(dp); dm1 = ntload4(dp + 1); dm2 = ntload4(dp + 2); dm3 = ntload4(dp + 3);
    } else if (c == 3) {
      const float4* sp = (const float4*)(xout + (size_t)vdst * D_ + t8 * 16);
      pf0 = sp[0]; pf1 = sp[1]; pf2 = sp[2]; pf3 = sp[3];
    } else if (c == 4) {
      const float4* sp = (const float4*)(xout + (size_t)vdst * D_ + 128 + t8 * 16);
      pf0 = sp[0]; pf1 = sp[1]; pf2 = sp[2]; pf3 = sp[3];
    }
    __syncthreads();
#pragma unroll
    for (int kk = 0; kk < 4; ++kk) {
      bf16_8 a0 = frag16(&sA[r16][kk * 32 + quad * 8]);
      bf16_8 a1 = frag16(&sA[16 + r16][kk * 32 + quad * 8]);
#pragma unroll
      for (int i = 0; i < 8; ++i) {
        const unsigned short* bp =
            wb1 + (size_t)(wv * 128 + i * 16 + r16) * 768 + k0 + kk * 32 + quad * 8;
        bf16_8 bf = frag16(bp);
        acc1[i][0] = __builtin_amdgcn_mfma_f32_16x16x32_bf16(a0, bf, acc1[i][0], 0, 0, 0);
        acc1[i][1] = __builtin_amdgcn_mfma_f32_16x16x32_bf16(a1, bf, acc1[i][1], 0, 0, 0);
      }
    }
  }
#pragma unroll
  for (int i = 0; i < 8; ++i) {
    int col = wv * 128 + i * 16 + r16;
    float bb = b1[col];
#pragma unroll
    for (int m = 0; m < 2; ++m)
#pragma unroll
      for (int r = 0; r < 4; ++r) {
        int row = m * 16 + quad * 4 + r;
        sT1[row][col] = f2b(gelu_exact(acc1[i][m][r] + bb));
      }
  }
  __syncthreads();

  f32x4 acc2[4][2];
#pragma unroll
  for (int i = 0; i < 4; ++i) { acc2[i][0] = zz; acc2[i][1] = zz; }
#pragma unroll 4
  for (int ks = 0; ks < 16; ++ks) {
    bf16_8 a0 = frag16(&sT1[r16][ks * 32 + quad * 8]);
    bf16_8 a1 = frag16(&sT1[16 + r16][ks * 32 + quad * 8]);
#pragma unroll
    for (int i = 0; i < 4; ++i) {
      const unsigned short* bp =
          wb2 + (size_t)(wv * 64 + i * 16 + r16) * 512 + ks * 32 + quad * 8;
      bf16_8 bf = frag16(bp);
      acc2[i][0] = __builtin_amdgcn_mfma_f32_16x16x32_bf16(a0, bf, acc2[i][0], 0, 0, 0);
      acc2[i][1] = __builtin_amdgcn_mfma_f32_16x16x32_bf16(a1, bf, acc2[i][1], 0, 0, 0);
    }
  }
#pragma unroll
  for (int i = 0; i < 4; ++i) {
    int col = wv * 64 + i * 16 + r16;
    float bb = b2[col];
#pragma unroll
    for (int m = 0; m < 2; ++m)
#pragma unroll
      for (int r = 0; r < 4; ++r) {
        int row = m * 16 + quad * 4 + r;
        sT2[row][col] = f2b(gelu_exact(acc2[i][m][r] + bb));
      }
  }
  __syncthreads();

  if (wv < 2) {
    f32x4 acc3 = zz;
#pragma unroll
    for (int ks = 0; ks < 8; ++ks) {
      bf16_8 a = frag16(&sT2[wv * 16 + r16][ks * 32 + quad * 8]);
      bf16_8 b = frag16(wb3 + (size_t)r16 * 256 + ks * 32 + quad * 8);
      acc3 = __builtin_amdgcn_mfma_f32_16x16x32_bf16(a, b, acc3, 0, 0, 0);
    }
    float bb = b3[r16];
#pragma unroll
    for (int r = 0; r < 4; ++r) {
      int row = wv * 16 + quad * 4 + r;
      __builtin_nontemporal_store(acc3[r] + bb, &dmo[(size_t)(e0 + row) * DIN_ + r16]);
    }
  }
}

extern "C" void kernel_launch(void* const* d_in, const int* in_sizes, int n_in,
                              void* d_out, int out_size, void* d_ws, size_t ws_size,
                              hipStream_t stream) {
  const float* input = (const float*)d_in[0];
  const int*   adj   = (const int*)d_in[1];
  const float* h0    = (const float*)d_in[2];
  const void*  lamda = d_in[3];
  const float* alpha = (const float*)d_in[4];
  const void*  lll   = d_in[5];
  const float* dmap  = (const float*)d_in[6];
  const float* nrm   = (const float*)d_in[7];
  const float* Wl    = (const float*)d_in[8];
  const float* Wg    = (const float*)d_in[9];
  const float* lin_w = (const float*)d_in[10];
  const float* lin_b = (const float*)d_in[11];
  const float* w1    = (const float*)d_in[12];
  const float* b1    = (const float*)d_in[13];
  const float* w2    = (const float*)d_in[14];
  const float* b2    = (const float*)d_in[15];
  const float* w3    = (const float*)d_in[16];
  const float* b3    = (const float*)d_in[17];
  const float* ipw   = (const float*)d_in[18];
  const float* ipb   = (const float*)d_in[19];
  const float* opw   = (const float*)d_in[20];
  const float* opb   = (const float*)d_in[21];
  float* out = (float*)d_out;
  float* dmo = out + (size_t)N_ * D_;

  // ---- workspace layout ----
  float* ws   = (float*)d_ws;
  float* xout = ws;                               // N*D f32
  float* qkv  = xout + (size_t)N_ * D_;           // N*3D f32
  float* atto = qkv  + (size_t)N_ * 3 * D_;       // N*D f32
  float* hgl  = atto + (size_t)N_ * D_;           // N*D f32
  unsigned short* wb1 = (unsigned short*)(hgl + (size_t)N_ * D_);  // 512*768
  unsigned short* wb2 = wb1 + 512 * 768;          // 256*512
  unsigned short* wb3 = wb2 + 256 * 512;          // 16*256
  unsigned short* Qb  = wb3 + 16 * 256;           // 2*N*128
  unsigned short* Kb  = Qb + 2 * N_ * HD_;        // 2*N*128
  unsigned short* Vt  = Kb + 2 * N_ * HD_;        // 2*128*N
  unsigned short* t1b = Vt + 2 * HD_ * N_;        // E*512  (fast path only)
  unsigned short* t2b = t1b + (size_t)E_ * 512;   // E*256  (fast path; aliases eab)
  unsigned short* eab = t2b;                      // E*256  (consumed before t2 written)
  int* cnt  = (int*)(t2b + (size_t)E_ * 256);     // 4096
  int* off  = cnt + 4096;                         // 4097
  int* cur  = off + 4100;                         // 4096
  int* perm = cur + 4096;                         // E
  const size_t fast_need = (size_t)((char*)(perm + E_) - (char*)d_ws);
  const bool fast = ws_size >= fast_need;

  // bf16 weight conversion (native [out,in] layout == MFMA B-frag layout)
  k_f2b<<<dim3((512 * 768 + 255) / 256), 256, 0, stream>>>(w1, wb1, 512 * 768);
  k_f2b<<<dim3((256 * 512 + 255) / 256), 256, 0, stream>>>(w2, wb2, 256 * 512);
  k_f2b<<<dim3((16 * 256 + 255) / 256), 256, 0, stream>>>(w3, wb3, 16 * 256);

  if (fast) {
    // edge_attr once, CSR build, then gather-based aggregation (no atomics on xout)
    k_edge_attr<<<dim3(E_ / 16), 256, 0, stream>>>(dmap, lin_w, lin_b, eab);
    k_zero<<<dim3(16), 256, 0, stream>>>(cnt, 4096);
    k_hist<<<dim3(E_ / 256), 256, 0, stream>>>(adj, cnt);
    k_scan<<<dim3(1), 1024, 0, stream>>>(cnt, off, cur);
    k_bucket<<<dim3(E_ / 256), 256, 0, stream>>>(adj, cur, perm);
    k_gather<<<dim3(N_), 256, 0, stream>>>(input, adj, eab, nrm, off, perm, xout);
  } else {
    k_copy4<<<dim3(N_ * D_ / 4 / 256), 256, 0, stream>>>((const float4*)input, (float4*)xout,
                                                         N_ * D_ / 4);
    k_scatter<<<dim3(E_ / 4), 256, 0, stream>>>(input, adj, dmap, nrm, lin_w, lin_b, xout);
  }

  // MHA: qkv proj -> bf16 split/transpose -> MFMA flash attention -> out_proj
  k_gemm_bt<<<dim3(D3_ / 64, N_ / 64), 256, 0, stream>>>(input, ipw, ipb, qkv, N_, D3_, D_);
  k_qk2b<<<dim3(N_ * 512 / 8 / 256), 256, 0, stream>>>(qkv, Qb, Kb);
  k_v2t<<<dim3(N_ / 64, 2), 256, 0, stream>>>(qkv, Vt);
  k_attn_mfma<<<dim3(N_ / 16, 2), 256, 0, stream>>>(Qb, Kb, Vt, atto);
  k_gemm_bt<<<dim3(D_ / 64, N_ / 64), 256, 0, stream>>>(atto, opw, opb, hgl, N_, D_, D_);

  // output[N,D]
  k_final<<<dim3(4, N_ / 64), 256, 0, stream>>>(xout, hgl, h0, Wl, Wg, alpha, lamda, lll, out);

  // dm_out[E,16]
  if (fast) {
    k_mlp_gemm1<<<dim3(E_ / 128, 4), 256, 0, stream>>>(xout, adj, eab, wb1, b1, t1b);
    k_mlp_gemm2<<<dim3(E_ / 128, 2), 256, 0, stream>>>(t1b, wb2, b2, t2b);
    k_mlp_gemm3<<<dim3(E_ / 64), 256, 0, stream>>>(t2b, wb3, b3, dmo);
  } else {
    k_edge_mlp_mfma<<<dim3(E_ / 32), 256, 0, stream>>>(xout, adj, dmap, lin_w, lin_b,
                                                       wb1, b1, wb2, b2, wb3, b3, dmo);
  }
}